// Round 3
// baseline (1119.801 us; speedup 1.0000x reference)
//
#include <hip/hip_runtime.h>
#include <hip/hip_bf16.h>

// TripletMessage, CSR-grouped, atomic-free hot path, packed fp16 edge records.
// alpha[e,h] = lrelu( a0[dst,h] + a2[src,h] + <ea[e], v1[h]> )  (exp'd in k_place)
// out[n]    = (sum_e ex*e_ij*x_j / sum_e ex) @ Ws + bias

#define N_NODES 50000
#define CCH 64
#define HEADS 3
#define HC 192
#define NEG_SLOPE 0.2f

typedef _Float16 h2 __attribute__((ext_vector_type(2)));

__device__ __forceinline__ h2 uh(unsigned u) {
    union { unsigned u; h2 h; } x; x.u = u; return x.h;
}
__device__ __forceinline__ unsigned hu(float a, float b) {
    union { unsigned u; _Float16 h[2]; } x;
    x.h[0] = (_Float16)a; x.h[1] = (_Float16)b; return x.u;
}

// ---------- k_prep: v1[h][k] = sum_c We[k, h*64+c] * Watt[h,1,c] ------------
__global__ void k_prep(const float* __restrict__ We, const float* __restrict__ Watt,
                       float* __restrict__ v1) {
    int t = threadIdx.x;
    if (t >= HEADS * 16) return;
    int h = t / 16, k = t % 16;
    float s = 0.f;
    #pragma unroll
    for (int c = 0; c < CCH; ++c)
        s = fmaf(We[k * HC + h * CCH + c], Watt[h * HC + CCH + c], s);
    v1[t] = s;  // [h*16+k]
}

// ---------- k_xproj: x_proj(fp16, 4-packed per (n,c)) + a0/a2 ---------------
// 192 threads (wave==head), 16 nodes/block
__global__ __launch_bounds__(192) void k_xproj(
    const float* __restrict__ x, const float* __restrict__ Wn,
    const float* __restrict__ Watt, uint2* __restrict__ xph2,
    float* __restrict__ a0, float* __restrict__ a2) {
    __shared__ float xs[16 * CCH];           // 4 KB
    __shared__ _Float16 pack[16 * CCH * 4];  // 8 KB: [j][c][h(4)]
    int t = threadIdx.x;
    float wreg[CCH];
    #pragma unroll
    for (int k = 0; k < CCH; ++k) wreg[k] = Wn[k * HC + t];
    int base = blockIdx.x * 16;
    for (int i = t; i < 16 * CCH; i += 192) {
        int idx = base * CCH + i;
        xs[i] = (idx < N_NODES * CCH) ? x[idx] : 0.f;
    }
    __syncthreads();
    int h = t >> 6, c = t & 63;
    float w0 = Watt[h * HC + c];
    float w2 = Watt[h * HC + 2 * CCH + c];
    #pragma unroll 1
    for (int j = 0; j < 16; ++j) {
        int n = base + j;
        if (n >= N_NODES) break;
        float val = 0.f;
        #pragma unroll
        for (int k = 0; k < CCH; k += 4) {
            float4 xv = *(const float4*)&xs[j * CCH + k];
            val = fmaf(xv.x, wreg[k], val);
            val = fmaf(xv.y, wreg[k + 1], val);
            val = fmaf(xv.z, wreg[k + 2], val);
            val = fmaf(xv.w, wreg[k + 3], val);
        }
        pack[(j * CCH + c) * 4 + h] = (_Float16)val;
        if (h == 0) pack[(j * CCH + c) * 4 + 3] = (_Float16)0.f;
        float p0 = val * w0, p2 = val * w2;
        #pragma unroll
        for (int off = 32; off; off >>= 1) {
            p0 += __shfl_down(p0, off);
            p2 += __shfl_down(p2, off);
        }
        if (c == 0) { a0[n * HEADS + h] = p0; a2[n * HEADS + h] = p2; }
    }
    __syncthreads();
    const uint2* p2v = (const uint2*)pack;
    for (int i = t; i < 16 * CCH; i += 192) {
        int n = base + (i >> 6);
        if (n < N_NODES) xph2[(size_t)base * CCH + i] = p2v[i];
    }
}

// ---------- k_hist ----------------------------------------------------------
__global__ __launch_bounds__(256) void k_hist(const int* __restrict__ ei,
                                              int* __restrict__ cnt, int E) {
    int e = blockIdx.x * 256 + threadIdx.x;
    if (e < E) atomicAdd(&cnt[ei[E + e]], 1);
}

// ---------- k_scan: single block, chunked exclusive scan --------------------
__global__ __launch_bounds__(1024) void k_scan(const int* __restrict__ cnt,
                                               int* __restrict__ off,
                                               int* __restrict__ cursor) {
    const int CH = 49;  // 1024*49 = 50176 >= 50000
    __shared__ int wsum[16];
    int t = threadIdx.x, lane = t & 63, wid = t >> 6;
    int start = t * CH;
    int s = 0;
    #pragma unroll 1
    for (int i = 0; i < CH; ++i) {
        int idx = start + i;
        if (idx < N_NODES) s += cnt[idx];
    }
    int x = s;
    #pragma unroll
    for (int o = 1; o < 64; o <<= 1) {
        int y = __shfl_up(x, o);
        if (lane >= o) x += y;
    }
    if (lane == 63) wsum[wid] = x;
    __syncthreads();
    if (wid == 0) {
        int v = (lane < 16) ? wsum[lane] : 0;
        #pragma unroll
        for (int o = 1; o < 16; o <<= 1) {
            int y = __shfl_up(v, o);
            if (lane >= o) v += y;
        }
        if (lane < 16) wsum[lane] = v;
    }
    __syncthreads();
    int run = (wid > 0 ? wsum[wid - 1] : 0) + x - s;  // exclusive prefix
    #pragma unroll 1
    for (int i = 0; i < CH; ++i) {
        int idx = start + i;
        if (idx < N_NODES) {
            off[idx] = run; cursor[idx] = run;
            run += cnt[idx];
        }
    }
    if (t == 1023) off[N_NODES] = run;
}

// ---------- k_place: alpha->exp, pack 48B records into CSR slots ------------
// record @pos*48: uint4 at[0..7]fp16 | uint4 at[8..15]fp16 | float4{ex0,ex1,ex2,src}
__global__ __launch_bounds__(256) void k_place(
    const int* __restrict__ ei, const float* __restrict__ ea,
    const float* __restrict__ a0, const float* __restrict__ a2,
    const float* __restrict__ v1, int* __restrict__ cursor,
    char* __restrict__ edges, int E) {
    __shared__ float v1s[48];
    if (threadIdx.x < 48) v1s[threadIdx.x] = v1[threadIdx.x];
    __syncthreads();
    int e = blockIdx.x * 256 + threadIdx.x;
    if (e >= E) return;
    int src = ei[e], dst = ei[E + e];
    const float4* q = (const float4*)(ea + (size_t)e * 16);
    float4 q0 = q[0], q1 = q[1], q2 = q[2], q3 = q[3];
    float at[16] = {q0.x, q0.y, q0.z, q0.w, q1.x, q1.y, q1.z, q1.w,
                    q2.x, q2.y, q2.z, q2.w, q3.x, q3.y, q3.z, q3.w};
    float ex[HEADS];
    #pragma unroll
    for (int h = 0; h < HEADS; ++h) {
        float s = a0[dst * HEADS + h] + a2[src * HEADS + h];
        #pragma unroll
        for (int j = 0; j < 16; ++j) s = fmaf(at[j], v1s[h * 16 + j], s);
        s = (s >= 0.f) ? s : NEG_SLOPE * s;
        ex[h] = __expf(s);
    }
    int pos = atomicAdd(&cursor[dst], 1);
    char* rp = edges + (size_t)pos * 48;
    uint4 r0 = {hu(at[0], at[1]), hu(at[2], at[3]), hu(at[4], at[5]), hu(at[6], at[7])};
    uint4 r1 = {hu(at[8], at[9]), hu(at[10], at[11]), hu(at[12], at[13]), hu(at[14], at[15])};
    float4 r2 = {ex[0], ex[1], ex[2], __int_as_float(src)};
    *(uint4*)rp = r0;
    *(uint4*)(rp + 16) = r1;
    *(float4*)(rp + 32) = r2;
}

// ---------- k_msg: wave-per-node (work queue), no LDS, fp16 pk math ---------
__global__ __launch_bounds__(256, 6) void k_msg(
    const int* __restrict__ off, const char* __restrict__ edges,
    const uint2* __restrict__ xph2, const float* __restrict__ We,
    _Float16* __restrict__ rowsH, int* __restrict__ qc) {
    int lane = threadIdx.x & 63;
    // per-lane We columns as fp16 pairs: we2[h][q] = {We[2q][h*64+c], We[2q+1][h*64+c]}
    h2 we2[HEADS][8];
    #pragma unroll
    for (int h = 0; h < HEADS; ++h)
        #pragma unroll
        for (int qi = 0; qi < 8; ++qi) {
            float wa = We[(2 * qi) * HC + h * CCH + lane];
            float wb = We[(2 * qi + 1) * HC + h * CCH + lane];
            we2[h][qi] = uh(hu(wa, wb));
        }
    for (;;) {
        int n;
        if (lane == 0) n = atomicAdd(qc, 1);
        n = __shfl(n, 0);
        if (n >= N_NODES) break;
        int rs = off[n], re = off[n + 1];
        rs = __builtin_amdgcn_readfirstlane(rs);
        re = __builtin_amdgcn_readfirstlane(re);
        float acc0 = 0.f, acc1 = 0.f, acc2 = 0.f;
        float den0 = 0.f, den1 = 0.f, den2 = 0.f;
        const char* ep = edges + (size_t)rs * 48;
        for (int k = rs; k < re; ++k, ep += 48) {
            uint4 r0 = *(const uint4*)ep;
            uint4 r1 = *(const uint4*)(ep + 16);
            float4 r2 = *(const float4*)(ep + 32);
            int src = __builtin_amdgcn_readfirstlane(__float_as_int(r2.w));
            uint2 xv = xph2[(size_t)src * CCH + lane];
            h2 at2[8] = {uh(r0.x), uh(r0.y), uh(r0.z), uh(r0.w),
                         uh(r1.x), uh(r1.y), uh(r1.z), uh(r1.w)};
            h2 e0 = at2[0] * we2[0][0], e1 = at2[0] * we2[1][0], e2 = at2[0] * we2[2][0];
            #pragma unroll
            for (int qi = 1; qi < 8; ++qi) {
                e0 += at2[qi] * we2[0][qi];
                e1 += at2[qi] * we2[1][qi];
                e2 += at2[qi] * we2[2][qi];
            }
            float ev0 = (float)e0.x + (float)e0.y;
            float ev1 = (float)e1.x + (float)e1.y;
            float ev2 = (float)e2.x + (float)e2.y;
            h2 xa = uh(xv.x), xb = uh(xv.y);
            den0 += r2.x; den1 += r2.y; den2 += r2.z;
            acc0 = fmaf(r2.x * ev0, (float)xa.x, acc0);
            acc1 = fmaf(r2.y * ev1, (float)xa.y, acc1);
            acc2 = fmaf(r2.z * ev2, (float)xb.x, acc2);
        }
        size_t ro = (size_t)n * HC + lane;
        rowsH[ro]           = (_Float16)(acc0 / (den0 + 1e-16f));
        rowsH[ro + CCH]     = (_Float16)(acc1 / (den1 + 1e-16f));
        rowsH[ro + 2 * CCH] = (_Float16)(acc2 / (den2 + 1e-16f));
    }
}

// ---------- k_out: out = rows @ Ws + bias (Ws in LDS, 64 nodes/block) -------
__global__ __launch_bounds__(512) void k_out(
    const _Float16* __restrict__ rowsH, const float* __restrict__ Ws,
    const float* __restrict__ bias, float* __restrict__ out) {
    __shared__ float wss[HC * CCH];   // 48 KB
    __shared__ float rtile[8 * HC];   // 6 KB
    int t = threadIdx.x, wid = t >> 6, c = t & 63;
    {
        float4* d4 = (float4*)wss;
        const float4* s4 = (const float4*)Ws;
        for (int i = t; i < HC * CCH / 4; i += 512) d4[i] = s4[i];
    }
    float b = bias[c];
    int base = blockIdx.x * 64;
    #pragma unroll 1
    for (int it = 0; it < 8; ++it) {
        int gbase = base + it * 8;
        int vn = N_NODES - gbase;
        vn = vn < 0 ? 0 : (vn > 8 ? 8 : vn);
        int vu = vn * (HC / 2);  // valid uints (fp16 pairs)
        __syncthreads();
        const unsigned* rg = (const unsigned*)(rowsH + (size_t)gbase * HC);
        for (int i = t; i < 8 * HC / 2; i += 512) {
            h2 v = (i < vu) ? uh(rg[i]) : uh(0u);
            rtile[2 * i]     = (float)v.x;
            rtile[2 * i + 1] = (float)v.y;
        }
        __syncthreads();
        int n = gbase + wid;
        if (n < N_NODES) {
            float val = b;
            #pragma unroll
            for (int k = 0; k < HC; k += 4) {
                float4 r = *(const float4*)&rtile[wid * HC + k];
                val = fmaf(r.x, wss[k * CCH + c], val);
                val = fmaf(r.y, wss[(k + 1) * CCH + c], val);
                val = fmaf(r.z, wss[(k + 2) * CCH + c], val);
                val = fmaf(r.w, wss[(k + 3) * CCH + c], val);
            }
            out[(size_t)n * CCH + c] = val;
        }
    }
}

extern "C" void kernel_launch(void* const* d_in, const int* in_sizes, int n_in,
                              void* d_out, int out_size, void* d_ws, size_t ws_size,
                              hipStream_t stream) {
    const float* x    = (const float*)d_in[0];
    const int*   ei   = (const int*)d_in[1];
    const float* ea   = (const float*)d_in[2];
    const float* Wn   = (const float*)d_in[3];
    const float* We   = (const float*)d_in[4];
    const float* Watt = (const float*)d_in[5];
    const float* Ws   = (const float*)d_in[6];
    const float* bias = (const float*)d_in[7];
    float* out = (float*)d_out;

    const int E = in_sizes[1] / 2;

    // workspace layout (bytes, all regions 16B-aligned); total ~85.0 MB
    char* w = (char*)d_ws;
    size_t o = 0;
    int*   cnt    = (int*)(w + o);    o += 50048 * 4;   // zeroed
    int*   qc     = (int*)(w + o);    o += 64 * 4;      // zeroed (same memset)
    int*   off    = (int*)(w + o);    o += 50064 * 4;
    int*   cursor = (int*)(w + o);    o += 50048 * 4;
    float* v1     = (float*)(w + o);  o += 64 * 4;
    float* a0     = (float*)(w + o);  o += 150016 * 4;
    float* a2     = (float*)(w + o);  o += 150016 * 4;
    uint2* xph2   = (uint2*)(w + o);  o += (size_t)N_NODES * CCH * 8;
    _Float16* rowsH = (_Float16*)(w + o); o += (size_t)N_NODES * HC * 2;
    char*  edges  = w + o;            o += (size_t)E * 48;

    hipMemsetAsync(cnt, 0, (50048 + 64) * 4, stream);

    k_prep<<<1, 64, 0, stream>>>(We, Watt, v1);
    k_xproj<<<(N_NODES + 15) / 16, 192, 0, stream>>>(x, Wn, Watt, xph2, a0, a2);
    k_hist<<<(E + 255) / 256, 256, 0, stream>>>(ei, cnt, E);
    k_scan<<<1, 1024, 0, stream>>>(cnt, off, cursor);
    k_place<<<(E + 255) / 256, 256, 0, stream>>>(ei, ea, a0, a2, v1, cursor, edges, E);
    k_msg<<<2048, 256, 0, stream>>>(off, edges, xph2, We, rowsH, qc);
    k_out<<<(N_NODES + 63) / 64, 512, 0, stream>>>(rowsH, Ws, bias, out);
}

// Round 4
// 485.509 us; speedup vs baseline: 2.3064x; 2.3064x over previous
//
#include <hip/hip_runtime.h>
#include <hip/hip_bf16.h>

// TripletMessage, CSR-grouped, atomic-free hot path.
// k_place computes ex[h]=exp(lrelu(a0[dst,h]+a2[src,h]+<ea,v1[h]>)) and scatters
// 20B records {ex0,ex1,ex2,src,eorig} into CSR slots; k_msg streams records,
// broadcast-loads ea[eorig], gathers packed-fp16 x_proj[src], accumulates.

#define N_NODES 50000
#define CCH 64
#define HEADS 3
#define HC 192
#define NEG_SLOPE 0.2f
#define NWAVES 5120   // k_msg: 1280 blocks x 4 waves, exactly resident at 5 w/EU

typedef _Float16 h2 __attribute__((ext_vector_type(2)));
__device__ __forceinline__ h2 uh(unsigned u) {
    union { unsigned u; h2 h; } x; x.u = u; return x.h;
}

// ---------- k_prep: v1[h][k] = sum_c We[k, h*64+c] * Watt[h,1,c] ------------
__global__ void k_prep(const float* __restrict__ We, const float* __restrict__ Watt,
                       float* __restrict__ v1) {
    int t = threadIdx.x;
    if (t >= HEADS * 16) return;
    int h = t / 16, k = t % 16;
    float s = 0.f;
    #pragma unroll
    for (int c = 0; c < CCH; ++c)
        s = fmaf(We[k * HC + h * CCH + c], Watt[h * HC + CCH + c], s);
    v1[t] = s;  // [h*16+k]
}

// ---------- k_xproj: x_proj(fp16, 4-packed per (n,c)) + a0/a2 ---------------
__global__ __launch_bounds__(192) void k_xproj(
    const float* __restrict__ x, const float* __restrict__ Wn,
    const float* __restrict__ Watt, uint2* __restrict__ xph2,
    float* __restrict__ a0, float* __restrict__ a2) {
    __shared__ float xs[16 * CCH];           // 4 KB
    __shared__ _Float16 pack[16 * CCH * 4];  // 8 KB: [j][c][h(4)]
    int t = threadIdx.x;
    float wreg[CCH];
    #pragma unroll
    for (int k = 0; k < CCH; ++k) wreg[k] = Wn[k * HC + t];
    int base = blockIdx.x * 16;
    for (int i = t; i < 16 * CCH; i += 192) {
        int idx = base * CCH + i;
        xs[i] = (idx < N_NODES * CCH) ? x[idx] : 0.f;
    }
    __syncthreads();
    int h = t >> 6, c = t & 63;
    float w0 = Watt[h * HC + c];
    float w2 = Watt[h * HC + 2 * CCH + c];
    #pragma unroll 1
    for (int j = 0; j < 16; ++j) {
        int n = base + j;
        if (n >= N_NODES) break;
        float val = 0.f;
        #pragma unroll
        for (int k = 0; k < CCH; k += 4) {
            float4 xv = *(const float4*)&xs[j * CCH + k];
            val = fmaf(xv.x, wreg[k], val);
            val = fmaf(xv.y, wreg[k + 1], val);
            val = fmaf(xv.z, wreg[k + 2], val);
            val = fmaf(xv.w, wreg[k + 3], val);
        }
        pack[(j * CCH + c) * 4 + h] = (_Float16)val;
        if (h == 0) pack[(j * CCH + c) * 4 + 3] = (_Float16)0.f;
        float p0 = val * w0, p2 = val * w2;
        #pragma unroll
        for (int off = 32; off; off >>= 1) {
            p0 += __shfl_down(p0, off);
            p2 += __shfl_down(p2, off);
        }
        if (c == 0) { a0[n * HEADS + h] = p0; a2[n * HEADS + h] = p2; }
    }
    __syncthreads();
    const uint2* p2v = (const uint2*)pack;
    for (int i = t; i < 16 * CCH; i += 192) {
        int n = base + (i >> 6);
        if (n < N_NODES) xph2[(size_t)base * CCH + i] = p2v[i];
    }
}

// ---------- k_hist ----------------------------------------------------------
__global__ __launch_bounds__(256) void k_hist(const int* __restrict__ ei,
                                              int* __restrict__ cnt, int E) {
    int e = blockIdx.x * 256 + threadIdx.x;
    if (e < E) atomicAdd(&cnt[ei[E + e]], 1);
}

// ---------- k_scan: single block, coalesced tile scan -----------------------
__global__ __launch_bounds__(1024) void k_scan(const int* __restrict__ cnt,
                                               int* __restrict__ off,
                                               int* __restrict__ cursor) {
    __shared__ int wsum[16];
    __shared__ int carry_s;
    int t = threadIdx.x, lane = t & 63, wid = t >> 6;
    if (t == 0) carry_s = 0;
    __syncthreads();
    for (int base = 0; base < N_NODES; base += 1024) {
        int i = base + t;
        int v = (i < N_NODES) ? cnt[i] : 0;
        int x = v;
        #pragma unroll
        for (int o = 1; o < 64; o <<= 1) {
            int y = __shfl_up(x, o);
            if (lane >= o) x += y;
        }
        if (lane == 63) wsum[wid] = x;
        __syncthreads();
        if (wid == 0) {
            int s = (lane < 16) ? wsum[lane] : 0;
            #pragma unroll
            for (int o = 1; o < 16; o <<= 1) {
                int y = __shfl_up(s, o);
                if (lane >= o) s += y;
            }
            if (lane < 16) wsum[lane] = s;
        }
        __syncthreads();
        int woff = (wid > 0) ? wsum[wid - 1] : 0;
        int incl = carry_s + woff + x;
        int excl = incl - v;
        if (i < N_NODES) { off[i] = excl; cursor[i] = excl; }
        __syncthreads();
        if (t == 1023) carry_s = incl;
        __syncthreads();
    }
    if (t == 0) off[N_NODES] = carry_s;
}

// ---------- k_part: balanced node partition for NWAVES waves ----------------
__global__ __launch_bounds__(256) void k_part(const int* __restrict__ off,
                                              int* __restrict__ wstart, int E) {
    int w = blockIdx.x * 256 + threadIdx.x;
    if (w > NWAVES) return;
    if (w == NWAVES) { wstart[NWAVES] = N_NODES; return; }
    long tgt = (long)E * w / NWAVES;
    int lo = 0, hi = N_NODES;  // first n with off[n] >= tgt
    while (lo < hi) {
        int mid = (lo + hi) >> 1;
        if (off[mid] < (int)tgt) lo = mid + 1; else hi = mid;
    }
    wstart[w] = lo;
}

// ---------- k_place: exp(alpha) + 20B record scatter into CSR slots ---------
// record @pos*32: float4{ex0,ex1,ex2,src_bits} | int{eorig}
__global__ __launch_bounds__(256) void k_place(
    const int* __restrict__ ei, const float* __restrict__ ea,
    const float* __restrict__ a0, const float* __restrict__ a2,
    const float* __restrict__ v1, int* __restrict__ cursor,
    float* __restrict__ recs, int E) {
    __shared__ float v1s[48];
    if (threadIdx.x < 48) v1s[threadIdx.x] = v1[threadIdx.x];
    __syncthreads();
    int e = blockIdx.x * 256 + threadIdx.x;
    if (e >= E) return;
    int src = ei[e], dst = ei[E + e];
    const float4* q = (const float4*)(ea + (size_t)e * 16);
    float4 q0 = q[0], q1 = q[1], q2 = q[2], q3 = q[3];
    float at[16] = {q0.x, q0.y, q0.z, q0.w, q1.x, q1.y, q1.z, q1.w,
                    q2.x, q2.y, q2.z, q2.w, q3.x, q3.y, q3.z, q3.w};
    float ex[HEADS];
    #pragma unroll
    for (int h = 0; h < HEADS; ++h) {
        float s = a0[dst * HEADS + h] + a2[src * HEADS + h];
        #pragma unroll
        for (int j = 0; j < 16; ++j) s = fmaf(at[j], v1s[h * 16 + j], s);
        s = (s >= 0.f) ? s : NEG_SLOPE * s;
        ex[h] = __expf(s);
    }
    int pos = atomicAdd(&cursor[dst], 1);
    float* rp = recs + (size_t)pos * 8;
    float4 rA = {ex[0], ex[1], ex[2], __int_as_float(src)};
    *(float4*)rp = rA;
    ((int*)rp)[4] = e;
}

// ---------- k_msg: wave-per-node-run, pipelined, no LDS ---------------------
__global__ __launch_bounds__(256, 5) void k_msg(
    const int* __restrict__ off, const int* __restrict__ wstart,
    const float* __restrict__ recs, const float* __restrict__ ea,
    const uint2* __restrict__ xph2, const float* __restrict__ We,
    _Float16* __restrict__ rowsH) {
    int lane = threadIdx.x & 63;
    int w = blockIdx.x * 4 + (threadIdx.x >> 6);
    // per-lane We columns (fp32, register-resident: proven round 2)
    float weR[HEADS][16];
    #pragma unroll
    for (int h = 0; h < HEADS; ++h)
        #pragma unroll
        for (int j = 0; j < 16; ++j)
            weR[h][j] = We[j * HC + h * CCH + lane];

    int n0 = wstart[w], n1 = wstart[w + 1];
    n0 = __builtin_amdgcn_readfirstlane(n0);
    n1 = __builtin_amdgcn_readfirstlane(n1);
    if (n0 >= n1) return;

    int n = n0;
    int k    = __builtin_amdgcn_readfirstlane(off[n0]);
    int kend = __builtin_amdgcn_readfirstlane(off[n1]);
    int re   = __builtin_amdgcn_readfirstlane(off[n0 + 1]);

    float acc0 = 0.f, acc1 = 0.f, acc2 = 0.f;
    float den0 = 0.f, den1 = 0.f, den2 = 0.f;

    float4 rA;
    float4 q0, q1, q2, q3;
    uint2 xv;
    if (k < kend) {  // prologue: full load chain for edge k
        rA = *(const float4*)(recs + (size_t)k * 8);
        int eo = __builtin_amdgcn_readfirstlane(((const int*)(recs + (size_t)k * 8))[4]);
        int src = __builtin_amdgcn_readfirstlane(__float_as_int(rA.w));
        const float4* eq = (const float4*)(ea + (size_t)eo * 16);
        q0 = eq[0]; q1 = eq[1]; q2 = eq[2]; q3 = eq[3];
        xv = xph2[(size_t)src * CCH + lane];
    }

    #define FLUSH(nn)                                                      \
        {                                                                  \
            size_t ro = (size_t)(nn) * HC + lane;                          \
            rowsH[ro]           = (_Float16)(acc0 / (den0 + 1e-16f));      \
            rowsH[ro + CCH]     = (_Float16)(acc1 / (den1 + 1e-16f));      \
            rowsH[ro + 2 * CCH] = (_Float16)(acc2 / (den2 + 1e-16f));      \
            acc0 = acc1 = acc2 = den0 = den1 = den2 = 0.f;                 \
        }

    while (k < kend) {
        while (k == re) {  // wave-uniform node boundary
            FLUSH(n);
            ++n;
            re = __builtin_amdgcn_readfirstlane(off[n + 1]);
        }
        // prefetch next record (independent address)
        int kn = (k + 1 < kend) ? k + 1 : k;
        float4 rA_n = *(const float4*)(recs + (size_t)kn * 8);
        int eo_n = __builtin_amdgcn_readfirstlane(((const int*)(recs + (size_t)kn * 8))[4]);
        // compute edge k
        float ev0 = 0.f, ev1 = 0.f, ev2 = 0.f;
        #define STEP(f, j)                      \
            ev0 = fmaf(f, weR[0][j], ev0);      \
            ev1 = fmaf(f, weR[1][j], ev1);      \
            ev2 = fmaf(f, weR[2][j], ev2);
        STEP(q0.x, 0)  STEP(q0.y, 1)  STEP(q0.z, 2)  STEP(q0.w, 3)
        STEP(q1.x, 4)  STEP(q1.y, 5)  STEP(q1.z, 6)  STEP(q1.w, 7)
        STEP(q2.x, 8)  STEP(q2.y, 9)  STEP(q2.z, 10) STEP(q2.w, 11)
        STEP(q3.x, 12) STEP(q3.y, 13) STEP(q3.z, 14) STEP(q3.w, 15)
        #undef STEP
        h2 xa = uh(xv.x), xb = uh(xv.y);
        den0 += rA.x; den1 += rA.y; den2 += rA.z;
        acc0 = fmaf(rA.x * ev0, (float)xa.x, acc0);
        acc1 = fmaf(rA.y * ev1, (float)xa.y, acc1);
        acc2 = fmaf(rA.z * ev2, (float)xb.x, acc2);
        // issue dependent loads for edge k+1
        rA = rA_n;
        int src_n = __builtin_amdgcn_readfirstlane(__float_as_int(rA_n.w));
        const float4* eq = (const float4*)(ea + (size_t)eo_n * 16);
        q0 = eq[0]; q1 = eq[1]; q2 = eq[2]; q3 = eq[3];
        xv = xph2[(size_t)src_n * CCH + lane];
        ++k;
    }
    FLUSH(n);
    while (++n < n1) FLUSH(n);  // trailing empty nodes
    #undef FLUSH
}

// ---------- k_out: out = rows @ Ws + bias (Ws in LDS, 64 nodes/block) -------
__global__ __launch_bounds__(512) void k_out(
    const _Float16* __restrict__ rowsH, const float* __restrict__ Ws,
    const float* __restrict__ bias, float* __restrict__ out) {
    __shared__ float wss[HC * CCH];   // 48 KB
    __shared__ float rtile[8 * HC];   // 6 KB
    int t = threadIdx.x, wid = t >> 6, c = t & 63;
    {
        float4* d4 = (float4*)wss;
        const float4* s4 = (const float4*)Ws;
        for (int i = t; i < HC * CCH / 4; i += 512) d4[i] = s4[i];
    }
    float b = bias[c];
    int base = blockIdx.x * 64;
    #pragma unroll 1
    for (int it = 0; it < 8; ++it) {
        int gbase = base + it * 8;
        int vn = N_NODES - gbase;
        vn = vn < 0 ? 0 : (vn > 8 ? 8 : vn);
        int vu = vn * (HC / 2);
        __syncthreads();
        const unsigned* rg = (const unsigned*)(rowsH + (size_t)gbase * HC);
        for (int i = t; i < 8 * HC / 2; i += 512) {
            h2 v = (i < vu) ? uh(rg[i]) : uh(0u);
            rtile[2 * i]     = (float)v.x;
            rtile[2 * i + 1] = (float)v.y;
        }
        __syncthreads();
        int n = gbase + wid;
        if (n < N_NODES) {
            float val = b;
            #pragma unroll
            for (int k = 0; k < HC; k += 4) {
                float4 r = *(const float4*)&rtile[wid * HC + k];
                val = fmaf(r.x, wss[k * CCH + c], val);
                val = fmaf(r.y, wss[(k + 1) * CCH + c], val);
                val = fmaf(r.z, wss[(k + 2) * CCH + c], val);
                val = fmaf(r.w, wss[(k + 3) * CCH + c], val);
            }
            out[(size_t)n * CCH + c] = val;
        }
    }
}

extern "C" void kernel_launch(void* const* d_in, const int* in_sizes, int n_in,
                              void* d_out, int out_size, void* d_ws, size_t ws_size,
                              hipStream_t stream) {
    const float* x    = (const float*)d_in[0];
    const int*   ei   = (const int*)d_in[1];
    const float* ea   = (const float*)d_in[2];
    const float* Wn   = (const float*)d_in[3];
    const float* We   = (const float*)d_in[4];
    const float* Watt = (const float*)d_in[5];
    const float* Ws   = (const float*)d_in[6];
    const float* bias = (const float*)d_in[7];
    float* out = (float*)d_out;

    const int E = in_sizes[1] / 2;

    // workspace layout (bytes, 16B-aligned regions); total ~73 MB
    char* w = (char*)d_ws;
    size_t o = 0;
    int*   cnt    = (int*)(w + o);    o += 50048 * 4;   // zeroed
    int*   off    = (int*)(w + o);    o += 50064 * 4;
    int*   cursor = (int*)(w + o);    o += 50048 * 4;
    int*   wst    = (int*)(w + o);    o += (NWAVES + 16) * 4;
    float* v1     = (float*)(w + o);  o += 64 * 4;
    float* a0     = (float*)(w + o);  o += 150016 * 4;
    float* a2     = (float*)(w + o);  o += 150016 * 4;
    uint2* xph2   = (uint2*)(w + o);  o += (size_t)N_NODES * CCH * 8;
    _Float16* rowsH = (_Float16*)(w + o); o += (size_t)N_NODES * HC * 2;
    float* recs   = (float*)(w + o);  o += (size_t)E * 32;

    hipMemsetAsync(cnt, 0, 50048 * 4, stream);

    k_prep<<<1, 64, 0, stream>>>(We, Watt, v1);
    k_xproj<<<(N_NODES + 15) / 16, 192, 0, stream>>>(x, Wn, Watt, xph2, a0, a2);
    k_hist<<<(E + 255) / 256, 256, 0, stream>>>(ei, cnt, E);
    k_scan<<<1, 1024, 0, stream>>>(cnt, off, cursor);
    k_part<<<(NWAVES + 256) / 256, 256, 0, stream>>>(off, wst, E);
    k_place<<<(E + 255) / 256, 256, 0, stream>>>(ei, ea, a0, a2, v1, cursor, recs, E);
    k_msg<<<NWAVES / 4, 256, 0, stream>>>(off, wst, recs, ea, xph2, We, rowsH);
    k_out<<<(N_NODES + 63) / 64, 512, 0, stream>>>(rowsH, Ws, bias, out);
}

// Round 5
// 452.059 us; speedup vs baseline: 2.4771x; 1.0740x over previous
//
#include <hip/hip_runtime.h>
#include <hip/hip_bf16.h>

// TripletMessage, CSR-grouped, atomic-free hot path.
// k_place computes ex[h]=exp(lrelu(a0[dst,h]+a2[src,h]+<ea,v1[h]>)) and scatters
// 48B records {at[16]:fp16, ex0,ex1,ex2, src} into CSR slots; k_msg streams
// records sequentially, gathers packed-fp16 x_proj[src], accumulates, flushes
// per-node softmax-normalized rows; k_out applies @Ws + bias.

#define N_NODES 50000
#define CCH 64
#define HEADS 3
#define HC 192
#define NEG_SLOPE 0.2f
#define NWAVES 6144   // k_msg: 1536 blocks x 4 waves; 6 blocks/CU at (256,6)

typedef _Float16 h2 __attribute__((ext_vector_type(2)));
__device__ __forceinline__ h2 uh(unsigned u) {
    union { unsigned u; h2 h; } x; x.u = u; return x.h;
}
__device__ __forceinline__ unsigned hu(float a, float b) {
    union { unsigned u; _Float16 h[2]; } x;
    x.h[0] = (_Float16)a; x.h[1] = (_Float16)b; return x.u;
}

// ---------- k_prep: v1[h][k] = sum_c We[k, h*64+c] * Watt[h,1,c] ------------
__global__ void k_prep(const float* __restrict__ We, const float* __restrict__ Watt,
                       float* __restrict__ v1) {
    int t = threadIdx.x;
    if (t >= HEADS * 16) return;
    int h = t / 16, k = t % 16;
    float s = 0.f;
    #pragma unroll
    for (int c = 0; c < CCH; ++c)
        s = fmaf(We[k * HC + h * CCH + c], Watt[h * HC + CCH + c], s);
    v1[t] = s;  // [h*16+k]
}

// ---------- k_xproj: x_proj(fp16, 4-packed per (n,c)) + a0/a2 ---------------
__global__ __launch_bounds__(192) void k_xproj(
    const float* __restrict__ x, const float* __restrict__ Wn,
    const float* __restrict__ Watt, uint2* __restrict__ xph2,
    float* __restrict__ a0, float* __restrict__ a2) {
    __shared__ float xs[16 * CCH];           // 4 KB
    __shared__ _Float16 pack[16 * CCH * 4];  // 8 KB: [j][c][h(4)]
    int t = threadIdx.x;
    float wreg[CCH];
    #pragma unroll
    for (int k = 0; k < CCH; ++k) wreg[k] = Wn[k * HC + t];
    int base = blockIdx.x * 16;
    for (int i = t; i < 16 * CCH; i += 192) {
        int idx = base * CCH + i;
        xs[i] = (idx < N_NODES * CCH) ? x[idx] : 0.f;
    }
    __syncthreads();
    int h = t >> 6, c = t & 63;
    float w0 = Watt[h * HC + c];
    float w2 = Watt[h * HC + 2 * CCH + c];
    #pragma unroll 1
    for (int j = 0; j < 16; ++j) {
        int n = base + j;
        if (n >= N_NODES) break;
        float val = 0.f;
        #pragma unroll
        for (int k = 0; k < CCH; k += 4) {
            float4 xv = *(const float4*)&xs[j * CCH + k];
            val = fmaf(xv.x, wreg[k], val);
            val = fmaf(xv.y, wreg[k + 1], val);
            val = fmaf(xv.z, wreg[k + 2], val);
            val = fmaf(xv.w, wreg[k + 3], val);
        }
        pack[(j * CCH + c) * 4 + h] = (_Float16)val;
        if (h == 0) pack[(j * CCH + c) * 4 + 3] = (_Float16)0.f;
        float p0 = val * w0, p2 = val * w2;
        #pragma unroll
        for (int off = 32; off; off >>= 1) {
            p0 += __shfl_down(p0, off);
            p2 += __shfl_down(p2, off);
        }
        if (c == 0) { a0[n * HEADS + h] = p0; a2[n * HEADS + h] = p2; }
    }
    __syncthreads();
    const uint2* p2v = (const uint2*)pack;
    for (int i = t; i < 16 * CCH; i += 192) {
        int n = base + (i >> 6);
        if (n < N_NODES) xph2[(size_t)base * CCH + i] = p2v[i];
    }
}

// ---------- k_hist ----------------------------------------------------------
__global__ __launch_bounds__(256) void k_hist(const int* __restrict__ ei,
                                              int* __restrict__ cnt, int E) {
    int e = blockIdx.x * 256 + threadIdx.x;
    if (e < E) atomicAdd(&cnt[ei[E + e]], 1);
}

// ---------- parallel scan: k_bsum -> k_bscan -> k_fin -----------------------
// 49 blocks x 1024 threads cover 50176 >= N_NODES
__global__ __launch_bounds__(1024) void k_bsum(const int* __restrict__ cnt,
                                               int* __restrict__ bsum) {
    __shared__ int ws[16];
    int t = threadIdx.x, lane = t & 63, wid = t >> 6;
    int i = blockIdx.x * 1024 + t;
    int v = (i < N_NODES) ? cnt[i] : 0;
    #pragma unroll
    for (int o = 32; o; o >>= 1) v += __shfl_down(v, o);
    if (lane == 0) ws[wid] = v;
    __syncthreads();
    if (wid == 0) {
        int s = (lane < 16) ? ws[lane] : 0;
        #pragma unroll
        for (int o = 8; o; o >>= 1) s += __shfl_down(s, o);
        if (lane == 0) bsum[blockIdx.x] = s;
    }
}

__global__ __launch_bounds__(64) void k_bscan(const int* __restrict__ bsum,
                                              int* __restrict__ boff,
                                              int* __restrict__ off) {
    int t = threadIdx.x;
    int v = (t < 49) ? bsum[t] : 0;
    int x = v;
    #pragma unroll
    for (int o = 1; o < 64; o <<= 1) {
        int y = __shfl_up(x, o);
        if (t >= o) x += y;
    }
    if (t < 49) boff[t] = x - v;
    if (t == 48) off[N_NODES] = x;   // total E
}

__global__ __launch_bounds__(1024) void k_fin(const int* __restrict__ cnt,
                                              const int* __restrict__ boff,
                                              int* __restrict__ off,
                                              int* __restrict__ cursor) {
    __shared__ int ws[16];
    int t = threadIdx.x, lane = t & 63, wid = t >> 6;
    int i = blockIdx.x * 1024 + t;
    int v = (i < N_NODES) ? cnt[i] : 0;
    int x = v;
    #pragma unroll
    for (int o = 1; o < 64; o <<= 1) {
        int y = __shfl_up(x, o);
        if (lane >= o) x += y;
    }
    if (lane == 63) ws[wid] = x;
    __syncthreads();
    if (wid == 0) {
        int s = (lane < 16) ? ws[lane] : 0;
        #pragma unroll
        for (int o = 1; o < 16; o <<= 1) {
            int y = __shfl_up(s, o);
            if (lane >= o) s += y;
        }
        if (lane < 16) ws[lane] = s;
    }
    __syncthreads();
    int excl = boff[blockIdx.x] + (wid ? ws[wid - 1] : 0) + x - v;
    if (i < N_NODES) { off[i] = excl; cursor[i] = excl; }
}

// ---------- k_part: balanced node partition for NWAVES waves ----------------
__global__ __launch_bounds__(256) void k_part(const int* __restrict__ off,
                                              int* __restrict__ wstart, int E) {
    int w = blockIdx.x * 256 + threadIdx.x;
    if (w > NWAVES) return;
    if (w == NWAVES) { wstart[NWAVES] = N_NODES; return; }
    long tgt = (long)E * w / NWAVES;
    int lo = 0, hi = N_NODES;  // first n with off[n] >= tgt
    while (lo < hi) {
        int mid = (lo + hi) >> 1;
        if (off[mid] < (int)tgt) lo = mid + 1; else hi = mid;
    }
    wstart[w] = lo;
}

// ---------- k_place: exp(alpha) + 48B record scatter into CSR slots ---------
// record @pos*48: uint4 at[0..7]fp16 | uint4 at[8..15]fp16 | float4{ex0,ex1,ex2,src}
__global__ __launch_bounds__(256) void k_place(
    const int* __restrict__ ei, const float* __restrict__ ea,
    const float* __restrict__ a0, const float* __restrict__ a2,
    const float* __restrict__ v1, int* __restrict__ cursor,
    float* __restrict__ recs, int E) {
    __shared__ float v1s[48];
    if (threadIdx.x < 48) v1s[threadIdx.x] = v1[threadIdx.x];
    __syncthreads();
    int e = blockIdx.x * 256 + threadIdx.x;
    if (e >= E) return;
    int src = ei[e], dst = ei[E + e];
    const float4* q = (const float4*)(ea + (size_t)e * 16);
    float4 q0 = q[0], q1 = q[1], q2 = q[2], q3 = q[3];
    float at[16] = {q0.x, q0.y, q0.z, q0.w, q1.x, q1.y, q1.z, q1.w,
                    q2.x, q2.y, q2.z, q2.w, q3.x, q3.y, q3.z, q3.w};
    float ex[HEADS];
    #pragma unroll
    for (int h = 0; h < HEADS; ++h) {
        float s = a0[dst * HEADS + h] + a2[src * HEADS + h];
        #pragma unroll
        for (int j = 0; j < 16; ++j) s = fmaf(at[j], v1s[h * 16 + j], s);
        s = (s >= 0.f) ? s : NEG_SLOPE * s;
        ex[h] = __expf(s);
    }
    int pos = atomicAdd(&cursor[dst], 1);
    float* rp = recs + (size_t)pos * 12;
    uint4 r0 = {hu(at[0], at[1]), hu(at[2], at[3]), hu(at[4], at[5]), hu(at[6], at[7])};
    uint4 r1 = {hu(at[8], at[9]), hu(at[10], at[11]), hu(at[12], at[13]), hu(at[14], at[15])};
    float4 r2 = {ex[0], ex[1], ex[2], __int_as_float(src)};
    *(uint4*)rp = r0;
    *(uint4*)(rp + 4) = r1;
    *(float4*)(rp + 8) = r2;
}

// ---------- k_msg: wave-per-node-run, pipelined, no LDS ---------------------
__global__ __launch_bounds__(256, 6) void k_msg(
    const int* __restrict__ off, const int* __restrict__ wstart,
    const float* __restrict__ recs, const uint2* __restrict__ xph2,
    const float* __restrict__ We, _Float16* __restrict__ rowsH) {
    int lane = threadIdx.x & 63;
    int w = blockIdx.x * 4 + (threadIdx.x >> 6);
    // per-lane We columns (fp32, register-resident: proven rounds 2/4)
    float weR[HEADS][16];
    #pragma unroll
    for (int h = 0; h < HEADS; ++h)
        #pragma unroll
        for (int j = 0; j < 16; ++j)
            weR[h][j] = We[j * HC + h * CCH + lane];

    int n0 = wstart[w], n1 = wstart[w + 1];
    n0 = __builtin_amdgcn_readfirstlane(n0);
    n1 = __builtin_amdgcn_readfirstlane(n1);
    if (n0 >= n1) return;

    int n = n0;
    int k    = __builtin_amdgcn_readfirstlane(off[n0]);
    int kend = __builtin_amdgcn_readfirstlane(off[n1]);
    int re   = __builtin_amdgcn_readfirstlane(off[n0 + 1]);

    float acc0 = 0.f, acc1 = 0.f, acc2 = 0.f;
    float den0 = 0.f, den1 = 0.f, den2 = 0.f;

    uint4 U0, U1; float4 RX; uint2 xv;
    if (k < kend) {  // prologue: full load chain for edge k
        const float* rp = recs + (size_t)k * 12;
        U0 = *(const uint4*)rp;
        U1 = *(const uint4*)(rp + 4);
        RX = *(const float4*)(rp + 8);
        int src = __builtin_amdgcn_readfirstlane(__float_as_int(RX.w));
        xv = xph2[(size_t)src * CCH + lane];
    }

    #define FLUSH(nn)                                                      \
        {                                                                  \
            size_t ro = (size_t)(nn) * HC + lane;                          \
            rowsH[ro]           = (_Float16)(acc0 / (den0 + 1e-16f));      \
            rowsH[ro + CCH]     = (_Float16)(acc1 / (den1 + 1e-16f));      \
            rowsH[ro + 2 * CCH] = (_Float16)(acc2 / (den2 + 1e-16f));      \
            acc0 = acc1 = acc2 = den0 = den1 = den2 = 0.f;                 \
        }

    while (k < kend) {
        while (k == re) {  // wave-uniform node boundary
            FLUSH(n);
            ++n;
            re = __builtin_amdgcn_readfirstlane(off[n + 1]);
        }
        // prefetch next record (independent, sequential address)
        int kn = (k + 1 < kend) ? k + 1 : k;
        const float* rpn = recs + (size_t)kn * 12;
        uint4 U0n = *(const uint4*)rpn;
        uint4 U1n = *(const uint4*)(rpn + 4);
        float4 RXn = *(const float4*)(rpn + 8);
        // unpack current edge's fp16 attrs (broadcast-uniform values)
        float f0, f1, f2, f3, f4, f5, f6, f7, f8, f9, f10, f11, f12, f13, f14, f15;
        #define UNP(u, a, b) { h2 p_ = uh(u); a = (float)p_.x; b = (float)p_.y; }
        UNP(U0.x, f0, f1)   UNP(U0.y, f2, f3)   UNP(U0.z, f4, f5)   UNP(U0.w, f6, f7)
        UNP(U1.x, f8, f9)   UNP(U1.y, f10, f11) UNP(U1.z, f12, f13) UNP(U1.w, f14, f15)
        #undef UNP
        float ev0 = 0.f, ev1 = 0.f, ev2 = 0.f;
        #define STEP(f, j)                      \
            ev0 = fmaf(f, weR[0][j], ev0);      \
            ev1 = fmaf(f, weR[1][j], ev1);      \
            ev2 = fmaf(f, weR[2][j], ev2);
        STEP(f0, 0)   STEP(f1, 1)   STEP(f2, 2)   STEP(f3, 3)
        STEP(f4, 4)   STEP(f5, 5)   STEP(f6, 6)   STEP(f7, 7)
        STEP(f8, 8)   STEP(f9, 9)   STEP(f10, 10) STEP(f11, 11)
        STEP(f12, 12) STEP(f13, 13) STEP(f14, 14) STEP(f15, 15)
        #undef STEP
        h2 xa = uh(xv.x), xb = uh(xv.y);
        den0 += RX.x; den1 += RX.y; den2 += RX.z;
        acc0 = fmaf(RX.x * ev0, (float)xa.x, acc0);
        acc1 = fmaf(RX.y * ev1, (float)xa.y, acc1);
        acc2 = fmaf(RX.z * ev2, (float)xb.x, acc2);
        // rotate and issue dependent x_proj gather for edge k+1
        U0 = U0n; U1 = U1n; RX = RXn;
        int src_n = __builtin_amdgcn_readfirstlane(__float_as_int(RXn.w));
        xv = xph2[(size_t)src_n * CCH + lane];
        ++k;
    }
    FLUSH(n);
    while (++n < n1) FLUSH(n);  // trailing empty nodes
    #undef FLUSH
}

// ---------- k_out: out = rows @ Ws + bias (Ws in LDS, 64 nodes/block) -------
__global__ __launch_bounds__(512) void k_out(
    const _Float16* __restrict__ rowsH, const float* __restrict__ Ws,
    const float* __restrict__ bias, float* __restrict__ out) {
    __shared__ float wss[HC * CCH];   // 48 KB
    __shared__ float rtile[8 * HC];   // 6 KB
    int t = threadIdx.x, wid = t >> 6, c = t & 63;
    {
        float4* d4 = (float4*)wss;
        const float4* s4 = (const float4*)Ws;
        for (int i = t; i < HC * CCH / 4; i += 512) d4[i] = s4[i];
    }
    float b = bias[c];
    int base = blockIdx.x * 64;
    #pragma unroll 1
    for (int it = 0; it < 8; ++it) {
        int gbase = base + it * 8;
        int vn = N_NODES - gbase;
        vn = vn < 0 ? 0 : (vn > 8 ? 8 : vn);
        int vu = vn * (HC / 2);
        __syncthreads();
        const unsigned* rg = (const unsigned*)(rowsH + (size_t)gbase * HC);
        for (int i = t; i < 8 * HC / 2; i += 512) {
            h2 v = (i < vu) ? uh(rg[i]) : uh(0u);
            rtile[2 * i]     = (float)v.x;
            rtile[2 * i + 1] = (float)v.y;
        }
        __syncthreads();
        int n = gbase + wid;
        if (n < N_NODES) {
            float val = b;
            #pragma unroll
            for (int k = 0; k < HC; k += 4) {
                float4 r = *(const float4*)&rtile[wid * HC + k];
                val = fmaf(r.x, wss[k * CCH + c], val);
                val = fmaf(r.y, wss[(k + 1) * CCH + c], val);
                val = fmaf(r.z, wss[(k + 2) * CCH + c], val);
                val = fmaf(r.w, wss[(k + 3) * CCH + c], val);
            }
            out[(size_t)n * CCH + c] = val;
        }
    }
}

extern "C" void kernel_launch(void* const* d_in, const int* in_sizes, int n_in,
                              void* d_out, int out_size, void* d_ws, size_t ws_size,
                              hipStream_t stream) {
    const float* x    = (const float*)d_in[0];
    const int*   ei   = (const int*)d_in[1];
    const float* ea   = (const float*)d_in[2];
    const float* Wn   = (const float*)d_in[3];
    const float* We   = (const float*)d_in[4];
    const float* Watt = (const float*)d_in[5];
    const float* Ws   = (const float*)d_in[6];
    const float* bias = (const float*)d_in[7];
    float* out = (float*)d_out;

    const int E = in_sizes[1] / 2;

    // workspace layout (bytes, 16B-aligned regions); total ~85 MB
    char* w = (char*)d_ws;
    size_t o = 0;
    int*   cnt    = (int*)(w + o);    o += 50048 * 4;   // zeroed
    int*   off    = (int*)(w + o);    o += 50064 * 4;
    int*   cursor = (int*)(w + o);    o += 50048 * 4;
    int*   wst    = (int*)(w + o);    o += (NWAVES + 16) * 4;
    int*   bsum   = (int*)(w + o);    o += 64 * 4;
    int*   boff   = (int*)(w + o);    o += 64 * 4;
    float* v1     = (float*)(w + o);  o += 64 * 4;
    float* a0     = (float*)(w + o);  o += 150016 * 4;
    float* a2     = (float*)(w + o);  o += 150016 * 4;
    uint2* xph2   = (uint2*)(w + o);  o += (size_t)N_NODES * CCH * 8;
    _Float16* rowsH = (_Float16*)(w + o); o += (size_t)N_NODES * HC * 2;
    float* recs   = (float*)(w + o);  o += (size_t)E * 48;

    hipMemsetAsync(cnt, 0, 50048 * 4, stream);

    k_prep<<<1, 64, 0, stream>>>(We, Watt, v1);
    k_xproj<<<(N_NODES + 15) / 16, 192, 0, stream>>>(x, Wn, Watt, xph2, a0, a2);
    k_hist<<<(E + 255) / 256, 256, 0, stream>>>(ei, cnt, E);
    k_bsum<<<49, 1024, 0, stream>>>(cnt, bsum);
    k_bscan<<<1, 64, 0, stream>>>(bsum, boff, off);
    k_fin<<<49, 1024, 0, stream>>>(cnt, boff, off, cursor);
    k_part<<<(NWAVES + 256) / 256, 256, 0, stream>>>(off, wst, E);
    k_place<<<(E + 255) / 256, 256, 0, stream>>>(ei, ea, a0, a2, v1, cursor, recs, E);
    k_msg<<<NWAVES / 4, 256, 0, stream>>>(off, wst, recs, xph2, We, rowsH);
    k_out<<<(N_NODES + 63) / 64, 512, 0, stream>>>(rowsH, Ws, bias, out);
}

// Round 6
// 411.364 us; speedup vs baseline: 2.7222x; 1.0989x over previous
//
#include <hip/hip_runtime.h>
#include <hip/hip_bf16.h>

// TripletMessage, CSR-grouped, atomic-free hot path.
// k_place computes ex[h]=exp(lrelu(a0[dst,h]+a2[src,h]+<ea,v1[h]>)) and scatters
// 48B records {at[16]:fp16, ex0,ex1,ex2, src} into CSR slots; k_msg streams
// records sequentially, gathers packed-fp16 x_proj[src], recomputes e_ij via
// v_dot2_f32_f16, accumulates, flushes per-node rows; k_out applies @Ws + bias.

#define N_NODES 50000
#define CCH 64
#define HEADS 3
#define HC 192
#define NEG_SLOPE 0.2f
#define NWAVES 12288   // k_msg: 3072 blocks x 4 waves; 2x oversubscribed for tail

typedef _Float16 h2 __attribute__((ext_vector_type(2)));
__device__ __forceinline__ h2 uh(unsigned u) {
    union { unsigned u; h2 h; } x; x.u = u; return x.h;
}
__device__ __forceinline__ unsigned hu(float a, float b) {
    union { unsigned u; _Float16 h[2]; } x;
    x.h[0] = (_Float16)a; x.h[1] = (_Float16)b; return x.u;
}

// ---------- k_prep: v1[h][k] = sum_c We[k, h*64+c] * Watt[h,1,c] ------------
__global__ void k_prep(const float* __restrict__ We, const float* __restrict__ Watt,
                       float* __restrict__ v1) {
    int t = threadIdx.x;
    if (t >= HEADS * 16) return;
    int h = t / 16, k = t % 16;
    float s = 0.f;
    #pragma unroll
    for (int c = 0; c < CCH; ++c)
        s = fmaf(We[k * HC + h * CCH + c], Watt[h * HC + CCH + c], s);
    v1[t] = s;  // [h*16+k]
}

// ---------- k_xproj: x_proj(fp16, 4-packed per (n,c)) + a0/a2 ---------------
__global__ __launch_bounds__(192) void k_xproj(
    const float* __restrict__ x, const float* __restrict__ Wn,
    const float* __restrict__ Watt, uint2* __restrict__ xph2,
    float* __restrict__ a0, float* __restrict__ a2) {
    __shared__ float xs[16 * CCH];           // 4 KB
    __shared__ _Float16 pack[16 * CCH * 4];  // 8 KB: [j][c][h(4)]
    int t = threadIdx.x;
    float wreg[CCH];
    #pragma unroll
    for (int k = 0; k < CCH; ++k) wreg[k] = Wn[k * HC + t];
    int base = blockIdx.x * 16;
    for (int i = t; i < 16 * CCH; i += 192) {
        int idx = base * CCH + i;
        xs[i] = (idx < N_NODES * CCH) ? x[idx] : 0.f;
    }
    __syncthreads();
    int h = t >> 6, c = t & 63;
    float w0 = Watt[h * HC + c];
    float w2 = Watt[h * HC + 2 * CCH + c];
    #pragma unroll 1
    for (int j = 0; j < 16; ++j) {
        int n = base + j;
        if (n >= N_NODES) break;
        float val = 0.f;
        #pragma unroll
        for (int k = 0; k < CCH; k += 4) {
            float4 xv = *(const float4*)&xs[j * CCH + k];
            val = fmaf(xv.x, wreg[k], val);
            val = fmaf(xv.y, wreg[k + 1], val);
            val = fmaf(xv.z, wreg[k + 2], val);
            val = fmaf(xv.w, wreg[k + 3], val);
        }
        pack[(j * CCH + c) * 4 + h] = (_Float16)val;
        if (h == 0) pack[(j * CCH + c) * 4 + 3] = (_Float16)0.f;
        float p0 = val * w0, p2 = val * w2;
        #pragma unroll
        for (int off = 32; off; off >>= 1) {
            p0 += __shfl_down(p0, off);
            p2 += __shfl_down(p2, off);
        }
        if (c == 0) { a0[n * HEADS + h] = p0; a2[n * HEADS + h] = p2; }
    }
    __syncthreads();
    const uint2* p2v = (const uint2*)pack;
    for (int i = t; i < 16 * CCH; i += 192) {
        int n = base + (i >> 6);
        if (n < N_NODES) xph2[(size_t)base * CCH + i] = p2v[i];
    }
}

// ---------- k_hist ----------------------------------------------------------
__global__ __launch_bounds__(256) void k_hist(const int* __restrict__ ei,
                                              int* __restrict__ cnt, int E) {
    int e = blockIdx.x * 256 + threadIdx.x;
    if (e < E) atomicAdd(&cnt[ei[E + e]], 1);
}

// ---------- parallel scan: k_bsum -> k_bscan -> k_fin -----------------------
__global__ __launch_bounds__(1024) void k_bsum(const int* __restrict__ cnt,
                                               int* __restrict__ bsum) {
    __shared__ int ws[16];
    int t = threadIdx.x, lane = t & 63, wid = t >> 6;
    int i = blockIdx.x * 1024 + t;
    int v = (i < N_NODES) ? cnt[i] : 0;
    #pragma unroll
    for (int o = 32; o; o >>= 1) v += __shfl_down(v, o);
    if (lane == 0) ws[wid] = v;
    __syncthreads();
    if (wid == 0) {
        int s = (lane < 16) ? ws[lane] : 0;
        #pragma unroll
        for (int o = 8; o; o >>= 1) s += __shfl_down(s, o);
        if (lane == 0) bsum[blockIdx.x] = s;
    }
}

__global__ __launch_bounds__(64) void k_bscan(const int* __restrict__ bsum,
                                              int* __restrict__ boff,
                                              int* __restrict__ off) {
    int t = threadIdx.x;
    int v = (t < 49) ? bsum[t] : 0;
    int x = v;
    #pragma unroll
    for (int o = 1; o < 64; o <<= 1) {
        int y = __shfl_up(x, o);
        if (t >= o) x += y;
    }
    if (t < 49) boff[t] = x - v;
    if (t == 48) off[N_NODES] = x;   // total E
}

__global__ __launch_bounds__(1024) void k_fin(const int* __restrict__ cnt,
                                              const int* __restrict__ boff,
                                              int* __restrict__ off,
                                              int* __restrict__ cursor) {
    __shared__ int ws[16];
    int t = threadIdx.x, lane = t & 63, wid = t >> 6;
    int i = blockIdx.x * 1024 + t;
    int v = (i < N_NODES) ? cnt[i] : 0;
    int x = v;
    #pragma unroll
    for (int o = 1; o < 64; o <<= 1) {
        int y = __shfl_up(x, o);
        if (lane >= o) x += y;
    }
    if (lane == 63) ws[wid] = x;
    __syncthreads();
    if (wid == 0) {
        int s = (lane < 16) ? ws[lane] : 0;
        #pragma unroll
        for (int o = 1; o < 16; o <<= 1) {
            int y = __shfl_up(s, o);
            if (lane >= o) s += y;
        }
        if (lane < 16) ws[lane] = s;
    }
    __syncthreads();
    int excl = boff[blockIdx.x] + (wid ? ws[wid - 1] : 0) + x - v;
    if (i < N_NODES) { off[i] = excl; cursor[i] = excl; }
}

// ---------- k_part: balanced node partition for NWAVES waves ----------------
__global__ __launch_bounds__(256) void k_part(const int* __restrict__ off,
                                              int* __restrict__ wstart, int E) {
    int w = blockIdx.x * 256 + threadIdx.x;
    if (w > NWAVES) return;
    if (w == NWAVES) { wstart[NWAVES] = N_NODES; return; }
    long tgt = (long)E * w / NWAVES;
    int lo = 0, hi = N_NODES;  // first n with off[n] >= tgt
    while (lo < hi) {
        int mid = (lo + hi) >> 1;
        if (off[mid] < (int)tgt) lo = mid + 1; else hi = mid;
    }
    wstart[w] = lo;
}

// ---------- k_place: exp(alpha) + 48B record scatter into CSR slots ---------
// record @pos*48: uint4 at[0..7]fp16 | uint4 at[8..15]fp16 | float4{ex0,ex1,ex2,src}
__global__ __launch_bounds__(256) void k_place(
    const int* __restrict__ ei, const float* __restrict__ ea,
    const float* __restrict__ a0, const float* __restrict__ a2,
    const float* __restrict__ v1, int* __restrict__ cursor,
    float* __restrict__ recs, int E) {
    __shared__ float v1s[48];
    if (threadIdx.x < 48) v1s[threadIdx.x] = v1[threadIdx.x];
    __syncthreads();
    int e = blockIdx.x * 256 + threadIdx.x;
    if (e >= E) return;
    int src = ei[e], dst = ei[E + e];
    const float4* q = (const float4*)(ea + (size_t)e * 16);
    float4 q0 = q[0], q1 = q[1], q2 = q[2], q3 = q[3];
    float at[16] = {q0.x, q0.y, q0.z, q0.w, q1.x, q1.y, q1.z, q1.w,
                    q2.x, q2.y, q2.z, q2.w, q3.x, q3.y, q3.z, q3.w};
    float ex[HEADS];
    #pragma unroll
    for (int h = 0; h < HEADS; ++h) {
        float s = a0[dst * HEADS + h] + a2[src * HEADS + h];
        #pragma unroll
        for (int j = 0; j < 16; ++j) s = fmaf(at[j], v1s[h * 16 + j], s);
        s = (s >= 0.f) ? s : NEG_SLOPE * s;
        ex[h] = __expf(s);
    }
    int pos = atomicAdd(&cursor[dst], 1);
    float* rp = recs + (size_t)pos * 12;
    uint4 r0 = {hu(at[0], at[1]), hu(at[2], at[3]), hu(at[4], at[5]), hu(at[6], at[7])};
    uint4 r1 = {hu(at[8], at[9]), hu(at[10], at[11]), hu(at[12], at[13]), hu(at[14], at[15])};
    float4 r2 = {ex[0], ex[1], ex[2], __int_as_float(src)};
    *(uint4*)rp = r0;
    *(uint4*)(rp + 4) = r1;
    *(float4*)(rp + 8) = r2;
}

// ---------- k_msg: wave-per-node-run, pipelined, fdot2 inner, no LDS --------
__global__ __launch_bounds__(256, 6) void k_msg(
    const int* __restrict__ off, const int* __restrict__ wstart,
    const float* __restrict__ recs, const uint2* __restrict__ xph2,
    const float* __restrict__ We, _Float16* __restrict__ rowsH) {
    int lane = threadIdx.x & 63;
    int w = blockIdx.x * 4 + (threadIdx.x >> 6);
    // packed We pairs as explicit scalars (avoid array->scratch demotion, r3)
    #define WP(h, q) hu(We[(2*(q)) * HC + (h) * CCH + lane], \
                        We[(2*(q)+1) * HC + (h) * CCH + lane])
    unsigned w00 = WP(0,0), w01 = WP(0,1), w02 = WP(0,2), w03 = WP(0,3),
             w04 = WP(0,4), w05 = WP(0,5), w06 = WP(0,6), w07 = WP(0,7);
    unsigned w10 = WP(1,0), w11 = WP(1,1), w12 = WP(1,2), w13 = WP(1,3),
             w14 = WP(1,4), w15 = WP(1,5), w16 = WP(1,6), w17 = WP(1,7);
    unsigned w20 = WP(2,0), w21 = WP(2,1), w22 = WP(2,2), w23 = WP(2,3),
             w24 = WP(2,4), w25 = WP(2,5), w26 = WP(2,6), w27 = WP(2,7);
    #undef WP

    int n0 = wstart[w], n1 = wstart[w + 1];
    n0 = __builtin_amdgcn_readfirstlane(n0);
    n1 = __builtin_amdgcn_readfirstlane(n1);
    if (n0 >= n1) return;

    int n = n0;
    int k    = __builtin_amdgcn_readfirstlane(off[n0]);
    int kend = __builtin_amdgcn_readfirstlane(off[n1]);
    int re   = __builtin_amdgcn_readfirstlane(off[n0 + 1]);

    float acc0 = 0.f, acc1 = 0.f, acc2 = 0.f;
    float den0 = 0.f, den1 = 0.f, den2 = 0.f;

    uint4 U0, U1; float4 RX; uint2 xv;
    if (k < kend) {  // prologue: full load chain for edge k
        const float* rp = recs + (size_t)k * 12;
        U0 = *(const uint4*)rp;
        U1 = *(const uint4*)(rp + 4);
        RX = *(const float4*)(rp + 8);
        int src = __builtin_amdgcn_readfirstlane(__float_as_int(RX.w));
        xv = xph2[(size_t)src * CCH + lane];
    }

    #define FLUSH(nn)                                                      \
        {                                                                  \
            size_t ro = (size_t)(nn) * HC + lane;                          \
            rowsH[ro]           = (_Float16)(acc0 / (den0 + 1e-16f));      \
            rowsH[ro + CCH]     = (_Float16)(acc1 / (den1 + 1e-16f));      \
            rowsH[ro + 2 * CCH] = (_Float16)(acc2 / (den2 + 1e-16f));      \
            acc0 = acc1 = acc2 = den0 = den1 = den2 = 0.f;                 \
        }

    while (k < kend) {
        while (k == re) {  // wave-uniform node boundary
            FLUSH(n);
            ++n;
            re = __builtin_amdgcn_readfirstlane(off[n + 1]);
        }
        // prefetch next record (independent, sequential address)
        int kn = (k + 1 < kend) ? k + 1 : k;
        const float* rpn = recs + (size_t)kn * 12;
        uint4 U0n = *(const uint4*)rpn;
        uint4 U1n = *(const uint4*)(rpn + 4);
        float4 RXn = *(const float4*)(rpn + 8);
        // e_ij recompute: 24 x v_dot2_f32_f16 (fp32 accumulate)
        float ev0 = 0.f, ev1 = 0.f, ev2 = 0.f;
        #define D(u, wv, acc) acc = __builtin_amdgcn_fdot2(uh(u), uh(wv), acc, false);
        D(U0.x, w00, ev0) D(U0.x, w10, ev1) D(U0.x, w20, ev2)
        D(U0.y, w01, ev0) D(U0.y, w11, ev1) D(U0.y, w21, ev2)
        D(U0.z, w02, ev0) D(U0.z, w12, ev1) D(U0.z, w22, ev2)
        D(U0.w, w03, ev0) D(U0.w, w13, ev1) D(U0.w, w23, ev2)
        D(U1.x, w04, ev0) D(U1.x, w14, ev1) D(U1.x, w24, ev2)
        D(U1.y, w05, ev0) D(U1.y, w15, ev1) D(U1.y, w25, ev2)
        D(U1.z, w06, ev0) D(U1.z, w16, ev1) D(U1.z, w26, ev2)
        D(U1.w, w07, ev0) D(U1.w, w17, ev1) D(U1.w, w27, ev2)
        #undef D
        h2 xa = uh(xv.x), xb = uh(xv.y);
        den0 += RX.x; den1 += RX.y; den2 += RX.z;
        acc0 = fmaf(RX.x * ev0, (float)xa.x, acc0);
        acc1 = fmaf(RX.y * ev1, (float)xa.y, acc1);
        acc2 = fmaf(RX.z * ev2, (float)xb.x, acc2);
        // rotate and issue dependent x_proj gather for edge k+1
        U0 = U0n; U1 = U1n; RX = RXn;
        int src_n = __builtin_amdgcn_readfirstlane(__float_as_int(RXn.w));
        xv = xph2[(size_t)src_n * CCH + lane];
        ++k;
    }
    FLUSH(n);
    while (++n < n1) FLUSH(n);  // trailing empty nodes
    #undef FLUSH
}

// ---------- k_out: out = rows @ Ws + bias (Ws in LDS, 200 nodes/block) ------
__global__ __launch_bounds__(512) void k_out(
    const _Float16* __restrict__ rowsH, const float* __restrict__ Ws,
    const float* __restrict__ bias, float* __restrict__ out) {
    __shared__ float wss[HC * CCH];   // 48 KB
    __shared__ float rtile[8 * HC];   // 6 KB
    int t = threadIdx.x, wid = t >> 6, c = t & 63;
    {
        float4* d4 = (float4*)wss;
        const float4* s4 = (const float4*)Ws;
        for (int i = t; i < HC * CCH / 4; i += 512) d4[i] = s4[i];
    }
    float b = bias[c];
    int base = blockIdx.x * 200;
    #pragma unroll 1
    for (int it = 0; it < 25; ++it) {
        int gbase = base + it * 8;
        int vn = N_NODES - gbase;
        vn = vn < 0 ? 0 : (vn > 8 ? 8 : vn);
        int vu = vn * (HC / 2);
        __syncthreads();
        const unsigned* rg = (const unsigned*)(rowsH + (size_t)gbase * HC);
        for (int i = t; i < 8 * HC / 2; i += 512) {
            h2 v = (i < vu) ? uh(rg[i]) : uh(0u);
            rtile[2 * i]     = (float)v.x;
            rtile[2 * i + 1] = (float)v.y;
        }
        __syncthreads();
        int n = gbase + wid;
        if (n < N_NODES) {
            float val = b;
            #pragma unroll
            for (int k = 0; k < HC; k += 4) {
                float4 r = *(const float4*)&rtile[wid * HC + k];
                val = fmaf(r.x, wss[k * CCH + c], val);
                val = fmaf(r.y, wss[(k + 1) * CCH + c], val);
                val = fmaf(r.z, wss[(k + 2) * CCH + c], val);
                val = fmaf(r.w, wss[(k + 3) * CCH + c], val);
            }
            out[(size_t)n * CCH + c] = val;
        }
    }
}

extern "C" void kernel_launch(void* const* d_in, const int* in_sizes, int n_in,
                              void* d_out, int out_size, void* d_ws, size_t ws_size,
                              hipStream_t stream) {
    const float* x    = (const float*)d_in[0];
    const int*   ei   = (const int*)d_in[1];
    const float* ea   = (const float*)d_in[2];
    const float* Wn   = (const float*)d_in[3];
    const float* We   = (const float*)d_in[4];
    const float* Watt = (const float*)d_in[5];
    const float* Ws   = (const float*)d_in[6];
    const float* bias = (const float*)d_in[7];
    float* out = (float*)d_out;

    const int E = in_sizes[1] / 2;

    // workspace layout (bytes, 16B-aligned regions); total ~85 MB
    char* w = (char*)d_ws;
    size_t o = 0;
    int*   cnt    = (int*)(w + o);    o += 50048 * 4;   // zeroed
    int*   off    = (int*)(w + o);    o += 50064 * 4;
    int*   cursor = (int*)(w + o);    o += 50048 * 4;
    int*   wst    = (int*)(w + o);    o += (NWAVES + 16) * 4;
    int*   bsum   = (int*)(w + o);    o += 64 * 4;
    int*   boff   = (int*)(w + o);    o += 64 * 4;
    float* v1     = (float*)(w + o);  o += 64 * 4;
    float* a0     = (float*)(w + o);  o += 150016 * 4;
    float* a2     = (float*)(w + o);  o += 150016 * 4;
    uint2* xph2   = (uint2*)(w + o);  o += (size_t)N_NODES * CCH * 8;
    _Float16* rowsH = (_Float16*)(w + o); o += (size_t)N_NODES * HC * 2;
    float* recs   = (float*)(w + o);  o += (size_t)E * 48;

    hipMemsetAsync(cnt, 0, 50048 * 4, stream);

    k_prep<<<1, 64, 0, stream>>>(We, Watt, v1);
    k_xproj<<<(N_NODES + 15) / 16, 192, 0, stream>>>(x, Wn, Watt, xph2, a0, a2);
    k_hist<<<(E + 255) / 256, 256, 0, stream>>>(ei, cnt, E);
    k_bsum<<<49, 1024, 0, stream>>>(cnt, bsum);
    k_bscan<<<1, 64, 0, stream>>>(bsum, boff, off);
    k_fin<<<49, 1024, 0, stream>>>(cnt, boff, off, cursor);
    k_part<<<(NWAVES + 256) / 256, 256, 0, stream>>>(off, wst, E);
    k_place<<<(E + 255) / 256, 256, 0, stream>>>(ei, ea, a0, a2, v1, cursor, recs, E);
    k_msg<<<NWAVES / 4, 256, 0, stream>>>(off, wst, recs, xph2, We, rowsH);
    k_out<<<250, 512, 0, stream>>>(rowsH, Ws, bias, out);
}

// Round 7
// 377.231 us; speedup vs baseline: 2.9685x; 1.0905x over previous
//
#include <hip/hip_runtime.h>
#include <hip/hip_bf16.h>

// TripletMessage, CSR-grouped, atomic-free hot path.
// k_place computes ex[h]=exp(lrelu(a0[dst,h]+a2[src,h]+<ea,v1[h]>)) and scatters
// 48B records {at[16]:fp16, ex0,ex1,ex2, src} into CSR slots; k_msg streams
// records sequentially, gathers packed-fp16 x_proj[src], recomputes e_ij via
// v_dot2_f32_f16, accumulates, flushes per-node rows; k_out applies @Ws + bias
// via SMEM row-broadcast + register-resident fp16 Ws column (no LDS).

#define N_NODES 50000
#define CCH 64
#define HEADS 3
#define HC 192
#define NEG_SLOPE 0.2f
#define NWAVES 12288   // k_msg: 3072 blocks x 4 waves

typedef _Float16 h2 __attribute__((ext_vector_type(2)));
__device__ __forceinline__ h2 uh(unsigned u) {
    union { unsigned u; h2 h; } x; x.u = u; return x.h;
}
__device__ __forceinline__ unsigned hu(float a, float b) {
    union { unsigned u; _Float16 h[2]; } x;
    x.h[0] = (_Float16)a; x.h[1] = (_Float16)b; return x.u;
}

// ---------- k_hist (+ fused k_prep in block 0) ------------------------------
__global__ __launch_bounds__(256) void k_hist(const int* __restrict__ ei,
                                              int* __restrict__ cnt,
                                              const float* __restrict__ We,
                                              const float* __restrict__ Watt,
                                              float* __restrict__ v1, int E) {
    int e = blockIdx.x * 256 + threadIdx.x;
    if (e < E) atomicAdd(&cnt[ei[E + e]], 1);
    if (blockIdx.x == 0 && threadIdx.x < HEADS * 16) {
        int h = threadIdx.x / 16, k = threadIdx.x % 16;
        float s = 0.f;
        #pragma unroll
        for (int c = 0; c < CCH; ++c)
            s = fmaf(We[k * HC + h * CCH + c], Watt[h * HC + CCH + c], s);
        v1[threadIdx.x] = s;  // [h*16+k]
    }
}

// ---------- k_xproj: SMEM x-row broadcast, no x staging ---------------------
// 192 threads (wave==head), 16 nodes/block; pack LDS only for xph2 layout
__global__ __launch_bounds__(192) void k_xproj(
    const float* __restrict__ x, const float* __restrict__ Wn,
    const float* __restrict__ Watt, uint2* __restrict__ xph2,
    float* __restrict__ a0, float* __restrict__ a2) {
    __shared__ _Float16 pack[16 * CCH * 4];  // 8 KB: [j][c][h(4)]
    int t = threadIdx.x;
    float wreg[CCH];
    #pragma unroll
    for (int k = 0; k < CCH; ++k) wreg[k] = Wn[k * HC + t];  // coalesced
    int base = blockIdx.x * 16;
    int h = t >> 6, c = t & 63;
    float w0 = Watt[h * HC + c];
    float w2 = Watt[h * HC + 2 * CCH + c];
    int jmax = N_NODES - base; jmax = jmax > 16 ? 16 : jmax;
    #pragma unroll 1
    for (int j = 0; j < jmax; ++j) {
        const float* xr = x + (size_t)(base + j) * CCH;  // wave-uniform -> s_load
        float val = 0.f;
        #pragma unroll
        for (int k = 0; k < CCH; ++k) val = fmaf(xr[k], wreg[k], val);
        pack[(j * CCH + c) * 4 + h] = (_Float16)val;
        if (h == 0) pack[(j * CCH + c) * 4 + 3] = (_Float16)0.f;
        float p0 = val * w0, p2 = val * w2;
        #pragma unroll
        for (int off = 32; off; off >>= 1) {
            p0 += __shfl_down(p0, off);
            p2 += __shfl_down(p2, off);
        }
        if (c == 0) {
            a0[(base + j) * HEADS + h] = p0;
            a2[(base + j) * HEADS + h] = p2;
        }
    }
    __syncthreads();
    const uint2* p2v = (const uint2*)pack;
    for (int i = t; i < 16 * CCH; i += 192) {
        int n = base + (i >> 6);
        if (n < N_NODES) xph2[(size_t)base * CCH + i] = p2v[i];
    }
}

// ---------- k_bsum: per-1024-chunk sums -------------------------------------
__global__ __launch_bounds__(1024) void k_bsum(const int* __restrict__ cnt,
                                               int* __restrict__ bsum) {
    __shared__ int ws[16];
    int t = threadIdx.x, lane = t & 63, wid = t >> 6;
    int i = blockIdx.x * 1024 + t;
    int v = (i < N_NODES) ? cnt[i] : 0;
    #pragma unroll
    for (int o = 32; o; o >>= 1) v += __shfl_down(v, o);
    if (lane == 0) ws[wid] = v;
    __syncthreads();
    if (wid == 0) {
        int s = (lane < 16) ? ws[lane] : 0;
        #pragma unroll
        for (int o = 8; o; o >>= 1) s += __shfl_down(s, o);
        if (lane == 0) bsum[blockIdx.x] = s;
    }
}

// ---------- k_fin: local scan + inline bsum-scan (fused k_bscan) ------------
__global__ __launch_bounds__(1024) void k_fin(const int* __restrict__ cnt,
                                              const int* __restrict__ bsum,
                                              int* __restrict__ off,
                                              int* __restrict__ cursor) {
    __shared__ int ws[16];
    __shared__ int bof_s;
    int t = threadIdx.x, lane = t & 63, wid = t >> 6;
    int i = blockIdx.x * 1024 + t;
    int v = (i < N_NODES) ? cnt[i] : 0;
    int x = v;
    #pragma unroll
    for (int o = 1; o < 64; o <<= 1) {
        int y = __shfl_up(x, o);
        if (lane >= o) x += y;
    }
    if (lane == 63) ws[wid] = x;
    __syncthreads();
    if (wid == 0) {         // scan the 16 wave sums
        int s = (lane < 16) ? ws[lane] : 0;
        #pragma unroll
        for (int o = 1; o < 16; o <<= 1) {
            int y = __shfl_up(s, o);
            if (lane >= o) s += y;
        }
        if (lane < 16) ws[lane] = s;
    } else if (wid == 1) {  // scan bsum[49] for this block's base offset
        int bv = (lane < 49) ? bsum[lane] : 0;
        int bx = bv;
        #pragma unroll
        for (int o = 1; o < 64; o <<= 1) {
            int y = __shfl_up(bx, o);
            if (lane >= o) bx += y;
        }
        if (lane == (int)blockIdx.x) bof_s = bx - bv;
        if (blockIdx.x == 48 && lane == 48) off[N_NODES] = bx;  // total E
    }
    __syncthreads();
    int excl = bof_s + (wid ? ws[wid - 1] : 0) + x - v;
    if (i < N_NODES) { off[i] = excl; cursor[i] = excl; }
}

// ---------- k_part: balanced node partition for NWAVES waves ----------------
__global__ __launch_bounds__(256) void k_part(const int* __restrict__ off,
                                              int* __restrict__ wstart, int E) {
    int w = blockIdx.x * 256 + threadIdx.x;
    if (w > NWAVES) return;
    if (w == NWAVES) { wstart[NWAVES] = N_NODES; return; }
    long tgt = (long)E * w / NWAVES;
    int lo = 0, hi = N_NODES;  // first n with off[n] >= tgt
    while (lo < hi) {
        int mid = (lo + hi) >> 1;
        if (off[mid] < (int)tgt) lo = mid + 1; else hi = mid;
    }
    wstart[w] = lo;
}

// ---------- k_place: exp(alpha) + 48B record scatter (v1 via s_load) --------
__global__ __launch_bounds__(256) void k_place(
    const int* __restrict__ ei, const float* __restrict__ ea,
    const float* __restrict__ a0, const float* __restrict__ a2,
    const float* __restrict__ v1, int* __restrict__ cursor,
    float* __restrict__ recs, int E) {
    int e = blockIdx.x * 256 + threadIdx.x;
    if (e >= E) return;
    int src = ei[e], dst = ei[E + e];
    const float4* q = (const float4*)(ea + (size_t)e * 16);
    float4 q0 = q[0], q1 = q[1], q2 = q[2], q3 = q[3];
    float at[16] = {q0.x, q0.y, q0.z, q0.w, q1.x, q1.y, q1.z, q1.w,
                    q2.x, q2.y, q2.z, q2.w, q3.x, q3.y, q3.z, q3.w};
    float ex[HEADS];
    #pragma unroll
    for (int h = 0; h < HEADS; ++h) {
        float s = a0[dst * HEADS + h] + a2[src * HEADS + h];
        #pragma unroll
        for (int j = 0; j < 16; ++j) s = fmaf(at[j], v1[h * 16 + j], s);  // uniform
        s = (s >= 0.f) ? s : NEG_SLOPE * s;
        ex[h] = __expf(s);
    }
    int pos = atomicAdd(&cursor[dst], 1);
    float* rp = recs + (size_t)pos * 12;
    uint4 r0 = {hu(at[0], at[1]), hu(at[2], at[3]), hu(at[4], at[5]), hu(at[6], at[7])};
    uint4 r1 = {hu(at[8], at[9]), hu(at[10], at[11]), hu(at[12], at[13]), hu(at[14], at[15])};
    float4 r2 = {ex[0], ex[1], ex[2], __int_as_float(src)};
    *(uint4*)rp = r0;
    *(uint4*)(rp + 4) = r1;
    *(float4*)(rp + 8) = r2;
}

// ---------- k_msg: wave-per-node-run, pipelined, fdot2 inner, no LDS --------
// (unchanged from round 6: 91 us measured, do not touch)
__global__ __launch_bounds__(256, 6) void k_msg(
    const int* __restrict__ off, const int* __restrict__ wstart,
    const float* __restrict__ recs, const uint2* __restrict__ xph2,
    const float* __restrict__ We, _Float16* __restrict__ rowsH) {
    int lane = threadIdx.x & 63;
    int w = blockIdx.x * 4 + (threadIdx.x >> 6);
    #define WP(h, q) hu(We[(2*(q)) * HC + (h) * CCH + lane], \
                        We[(2*(q)+1) * HC + (h) * CCH + lane])
    unsigned w00 = WP(0,0), w01 = WP(0,1), w02 = WP(0,2), w03 = WP(0,3),
             w04 = WP(0,4), w05 = WP(0,5), w06 = WP(0,6), w07 = WP(0,7);
    unsigned w10 = WP(1,0), w11 = WP(1,1), w12 = WP(1,2), w13 = WP(1,3),
             w14 = WP(1,4), w15 = WP(1,5), w16 = WP(1,6), w17 = WP(1,7);
    unsigned w20 = WP(2,0), w21 = WP(2,1), w22 = WP(2,2), w23 = WP(2,3),
             w24 = WP(2,4), w25 = WP(2,5), w26 = WP(2,6), w27 = WP(2,7);
    #undef WP

    int n0 = wstart[w], n1 = wstart[w + 1];
    n0 = __builtin_amdgcn_readfirstlane(n0);
    n1 = __builtin_amdgcn_readfirstlane(n1);
    if (n0 >= n1) return;

    int n = n0;
    int k    = __builtin_amdgcn_readfirstlane(off[n0]);
    int kend = __builtin_amdgcn_readfirstlane(off[n1]);
    int re   = __builtin_amdgcn_readfirstlane(off[n0 + 1]);

    float acc0 = 0.f, acc1 = 0.f, acc2 = 0.f;
    float den0 = 0.f, den1 = 0.f, den2 = 0.f;

    uint4 U0, U1; float4 RX; uint2 xv;
    if (k < kend) {
        const float* rp = recs + (size_t)k * 12;
        U0 = *(const uint4*)rp;
        U1 = *(const uint4*)(rp + 4);
        RX = *(const float4*)(rp + 8);
        int src = __builtin_amdgcn_readfirstlane(__float_as_int(RX.w));
        xv = xph2[(size_t)src * CCH + lane];
    }

    #define FLUSH(nn)                                                      \
        {                                                                  \
            size_t ro = (size_t)(nn) * HC + lane;                          \
            rowsH[ro]           = (_Float16)(acc0 / (den0 + 1e-16f));      \
            rowsH[ro + CCH]     = (_Float16)(acc1 / (den1 + 1e-16f));      \
            rowsH[ro + 2 * CCH] = (_Float16)(acc2 / (den2 + 1e-16f));      \
            acc0 = acc1 = acc2 = den0 = den1 = den2 = 0.f;                 \
        }

    while (k < kend) {
        while (k == re) {
            FLUSH(n);
            ++n;
            re = __builtin_amdgcn_readfirstlane(off[n + 1]);
        }
        int kn = (k + 1 < kend) ? k + 1 : k;
        const float* rpn = recs + (size_t)kn * 12;
        uint4 U0n = *(const uint4*)rpn;
        uint4 U1n = *(const uint4*)(rpn + 4);
        float4 RXn = *(const float4*)(rpn + 8);
        float ev0 = 0.f, ev1 = 0.f, ev2 = 0.f;
        #define D(u, wv, acc) acc = __builtin_amdgcn_fdot2(uh(u), uh(wv), acc, false);
        D(U0.x, w00, ev0) D(U0.x, w10, ev1) D(U0.x, w20, ev2)
        D(U0.y, w01, ev0) D(U0.y, w11, ev1) D(U0.y, w21, ev2)
        D(U0.z, w02, ev0) D(U0.z, w12, ev1) D(U0.z, w22, ev2)
        D(U0.w, w03, ev0) D(U0.w, w13, ev1) D(U0.w, w23, ev2)
        D(U1.x, w04, ev0) D(U1.x, w14, ev1) D(U1.x, w24, ev2)
        D(U1.y, w05, ev0) D(U1.y, w15, ev1) D(U1.y, w25, ev2)
        D(U1.z, w06, ev0) D(U1.z, w16, ev1) D(U1.z, w26, ev2)
        D(U1.w, w07, ev0) D(U1.w, w17, ev1) D(U1.w, w27, ev2)
        #undef D
        h2 xa = uh(xv.x), xb = uh(xv.y);
        den0 += RX.x; den1 += RX.y; den2 += RX.z;
        acc0 = fmaf(RX.x * ev0, (float)xa.x, acc0);
        acc1 = fmaf(RX.y * ev1, (float)xa.y, acc1);
        acc2 = fmaf(RX.z * ev2, (float)xb.x, acc2);
        U0 = U0n; U1 = U1n; RX = RXn;
        int src_n = __builtin_amdgcn_readfirstlane(__float_as_int(RXn.w));
        xv = xph2[(size_t)src_n * CCH + lane];
        ++k;
    }
    FLUSH(n);
    while (++n < n1) FLUSH(n);
    #undef FLUSH
}

// ---------- k_out: SMEM row broadcast + register fp16 Ws column, no LDS -----
__global__ __launch_bounds__(256) void k_out(
    const _Float16* __restrict__ rowsH, const float* __restrict__ Ws,
    const float* __restrict__ bias, float* __restrict__ out) {
    int lane = threadIdx.x & 63;
    int wgid = __builtin_amdgcn_readfirstlane(blockIdx.x * 4 + (threadIdx.x >> 6));
    float b = bias[lane];
    // Ws column `lane` as 96 packed fp16 pairs in explicit scalar VGPRs
    #define WQ(q) hu(Ws[(2*(q)) * CCH + lane], Ws[(2*(q)+1) * CCH + lane])
    unsigned s00=WQ(0),  s01=WQ(1),  s02=WQ(2),  s03=WQ(3),  s04=WQ(4),  s05=WQ(5),  s06=WQ(6),  s07=WQ(7);
    unsigned s08=WQ(8),  s09=WQ(9),  s10=WQ(10), s11=WQ(11), s12=WQ(12), s13=WQ(13), s14=WQ(14), s15=WQ(15);
    unsigned s16=WQ(16), s17=WQ(17), s18=WQ(18), s19=WQ(19), s20=WQ(20), s21=WQ(21), s22=WQ(22), s23=WQ(23);
    unsigned s24=WQ(24), s25=WQ(25), s26=WQ(26), s27=WQ(27), s28=WQ(28), s29=WQ(29), s30=WQ(30), s31=WQ(31);
    unsigned s32=WQ(32), s33=WQ(33), s34=WQ(34), s35=WQ(35), s36=WQ(36), s37=WQ(37), s38=WQ(38), s39=WQ(39);
    unsigned s40=WQ(40), s41=WQ(41), s42=WQ(42), s43=WQ(43), s44=WQ(44), s45=WQ(45), s46=WQ(46), s47=WQ(47);
    unsigned s48=WQ(48), s49=WQ(49), s50=WQ(50), s51=WQ(51), s52=WQ(52), s53=WQ(53), s54=WQ(54), s55=WQ(55);
    unsigned s56=WQ(56), s57=WQ(57), s58=WQ(58), s59=WQ(59), s60=WQ(60), s61=WQ(61), s62=WQ(62), s63=WQ(63);
    unsigned s64=WQ(64), s65=WQ(65), s66=WQ(66), s67=WQ(67), s68=WQ(68), s69=WQ(69), s70=WQ(70), s71=WQ(71);
    unsigned s72=WQ(72), s73=WQ(73), s74=WQ(74), s75=WQ(75), s76=WQ(76), s77=WQ(77), s78=WQ(78), s79=WQ(79);
    unsigned s80=WQ(80), s81=WQ(81), s82=WQ(82), s83=WQ(83), s84=WQ(84), s85=WQ(85), s86=WQ(86), s87=WQ(87);
    unsigned s88=WQ(88), s89=WQ(89), s90=WQ(90), s91=WQ(91), s92=WQ(92), s93=WQ(93), s94=WQ(94), s95=WQ(95);
    #undef WQ
    #pragma unroll 1
    for (int n = wgid; n < N_NODES; n += 1024) {
        const unsigned* rp = (const unsigned*)(rowsH + (size_t)n * HC);  // uniform
        float a0_ = b, a1_ = 0.f, a2_ = 0.f, a3_ = 0.f;
        #define DQ(q, sreg, acc) acc = __builtin_amdgcn_fdot2(uh(rp[q]), uh(sreg), acc, false);
        DQ(0,s00,a0_)  DQ(1,s01,a1_)  DQ(2,s02,a2_)  DQ(3,s03,a3_)
        DQ(4,s04,a0_)  DQ(5,s05,a1_)  DQ(6,s06,a2_)  DQ(7,s07,a3_)
        DQ(8,s08,a0_)  DQ(9,s09,a1_)  DQ(10,s10,a2_) DQ(11,s11,a3_)
        DQ(12,s12,a0_) DQ(13,s13,a1_) DQ(14,s14,a2_) DQ(15,s15,a3_)
        DQ(16,s16,a0_) DQ(17,s17,a1_) DQ(18,s18,a2_) DQ(19,s19,a3_)
        DQ(20,s20,a0_) DQ(21,s21,a1_) DQ(22,s22,a2_) DQ(23,s23,a3_)
        DQ(24,s24,a0_) DQ(25,s25,a1_) DQ(26,s26,a2_) DQ(27,s27,a3_)
        DQ(28,s28,a0_) DQ(29,s29,a1_) DQ(30,s30,a2_) DQ(31,s31,a3_)
        DQ(32,s32,a0_) DQ(33,s33,a1_) DQ(34,s34,a2_) DQ(35,s35,a3_)
        DQ(36,s36,a0_) DQ(37,s37,a1_) DQ(38,s38,a2_) DQ(39,s39,a3_)
        DQ(40,s40,a0_) DQ(41,s41,a1_) DQ(42,s42,a2_) DQ(43,s43,a3_)
        DQ(44,s44,a0_) DQ(45,s45,a1_) DQ(46,s46,a2_) DQ(47,s47,a3_)
        DQ(48,s48,a0_) DQ(49,s49,a1_) DQ(50,s50,a2_) DQ(51,s51,a3_)
        DQ(52,s52,a0_) DQ(53,s53,a1_) DQ(54,s54,a2_) DQ(55,s55,a3_)
        DQ(56,s56,a0_) DQ(57,s57,a1_) DQ(58,s58,a2_) DQ(59,s59,a3_)
        DQ(60,s60,a0_) DQ(61,s61,a1_) DQ(62,s62,a2_) DQ(63,s63,a3_)
        DQ(64,s64,a0_) DQ(65,s65,a1_) DQ(66,s66,a2_) DQ(67,s67,a3_)
        DQ(68,s68,a0_) DQ(69,s69,a1_) DQ(70,s70,a2_) DQ(71,s71,a3_)
        DQ(72,s72,a0_) DQ(73,s73,a1_) DQ(74,s74,a2_) DQ(75,s75,a3_)
        DQ(76,s76,a0_) DQ(77,s77,a1_) DQ(78,s78,a2_) DQ(79,s79,a3_)
        DQ(80,s80,a0_) DQ(81,s81,a1_) DQ(82,s82,a2_) DQ(83,s83,a3_)
        DQ(84,s84,a0_) DQ(85,s85,a1_) DQ(86,s86,a2_) DQ(87,s87,a3_)
        DQ(88,s88,a0_) DQ(89,s89,a1_) DQ(90,s90,a2_) DQ(91,s91,a3_)
        DQ(92,s92,a0_) DQ(93,s93,a1_) DQ(94,s94,a2_) DQ(95,s95,a3_)
        #undef DQ
        out[(size_t)n * CCH + lane] = (a0_ + a1_) + (a2_ + a3_);
    }
}

extern "C" void kernel_launch(void* const* d_in, const int* in_sizes, int n_in,
                              void* d_out, int out_size, void* d_ws, size_t ws_size,
                              hipStream_t stream) {
    const float* x    = (const float*)d_in[0];
    const int*   ei   = (const int*)d_in[1];
    const float* ea   = (const float*)d_in[2];
    const float* Wn   = (const float*)d_in[3];
    const float* We   = (const float*)d_in[4];
    const float* Watt = (const float*)d_in[5];
    const float* Ws   = (const float*)d_in[6];
    const float* bias = (const float*)d_in[7];
    float* out = (float*)d_out;

    const int E = in_sizes[1] / 2;

    // workspace layout (bytes, 16B-aligned regions); total ~85 MB
    char* w = (char*)d_ws;
    size_t o = 0;
    int*   cnt    = (int*)(w + o);    o += 50048 * 4;   // zeroed
    int*   off    = (int*)(w + o);    o += 50064 * 4;
    int*   cursor = (int*)(w + o);    o += 50048 * 4;
    int*   wst    = (int*)(w + o);    o += (NWAVES + 16) * 4;
    int*   bsum   = (int*)(w + o);    o += 64 * 4;
    float* v1     = (float*)(w + o);  o += 64 * 4;
    float* a0     = (float*)(w + o);  o += 150016 * 4;
    float* a2     = (float*)(w + o);  o += 150016 * 4;
    uint2* xph2   = (uint2*)(w + o);  o += (size_t)N_NODES * CCH * 8;
    _Float16* rowsH = (_Float16*)(w + o); o += (size_t)N_NODES * HC * 2;
    float* recs   = (float*)(w + o);  o += (size_t)E * 48;

    hipMemsetAsync(cnt, 0, 50048 * 4, stream);

    k_hist<<<(E + 255) / 256, 256, 0, stream>>>(ei, cnt, We, Watt, v1, E);
    k_xproj<<<(N_NODES + 15) / 16, 192, 0, stream>>>(x, Wn, Watt, xph2, a0, a2);
    k_bsum<<<49, 1024, 0, stream>>>(cnt, bsum);
    k_fin<<<49, 1024, 0, stream>>>(cnt, bsum, off, cursor);
    k_part<<<(NWAVES + 256) / 256, 256, 0, stream>>>(off, wst, E);
    k_place<<<(E + 255) / 256, 256, 0, stream>>>(ei, ea, a0, a2, v1, cursor, recs, E);
    k_msg<<<NWAVES / 4, 256, 0, stream>>>(off, wst, recs, xph2, We, rowsH);
    k_out<<<256, 256, 0, stream>>>(rowsH, Ws, bias, out);
}

// Round 8
// 372.137 us; speedup vs baseline: 3.0091x; 1.0137x over previous
//
#include <hip/hip_runtime.h>
#include <hip/hip_bf16.h>

// TripletMessage, CSR-grouped, atomic-free hot path.
// k_front: x_proj(fp16 packed) + a0/a2 + dst histogram + v1 precompute (fused).
// k_scan49: prefix-scan + balanced wave partition (grid barriers, 1 launch).
// k_place: ex[h]=exp(lrelu(a0+a2+<ea,v1>)), 48B CSR records {at fp16, ex, src}.
// k_msg: streams records, gathers packed-fp16 x_proj[src], fdot2 e_ij, flush.
// k_out: rows @ Ws + bias via SMEM row broadcast + register fp16 Ws column.

#define N_NODES 50000
#define CCH 64
#define HEADS 3
#define HC 192
#define NEG_SLOPE 0.2f
#define NWAVES 12288   // k_msg: 3072 blocks x 4 waves
#define NBX 3125       // k_front xproj blocks (16 nodes each)
#define NSCAN 49       // scan blocks (49*1024 >= N_NODES)

typedef _Float16 h2 __attribute__((ext_vector_type(2)));
__device__ __forceinline__ h2 uh(unsigned u) {
    union { unsigned u; h2 h; } x; x.u = u; return x.h;
}
__device__ __forceinline__ unsigned hu(float a, float b) {
    union { unsigned u; _Float16 h[2]; } x;
    x.h[0] = (_Float16)a; x.h[1] = (_Float16)b; return x.u;
}

// device-scope grid barrier (all blocks resident; bar zeroed pre-launch)
__device__ __forceinline__ void gbar(int* bar, int phase, int nb) {
    __syncthreads();
    if (threadIdx.x == 0) {
        __threadfence();
        __hip_atomic_fetch_add(&bar[phase], 1, __ATOMIC_ACQ_REL,
                               __HIP_MEMORY_SCOPE_AGENT);
        while (__hip_atomic_load(&bar[phase], __ATOMIC_ACQUIRE,
                                 __HIP_MEMORY_SCOPE_AGENT) < nb) {}
        __threadfence();
    }
    __syncthreads();
}

// ---------- k_front: fused xproj | hist | prep ------------------------------
// blocks [0,NBX): xproj 16 nodes each (192 thr, wave==head)
// blocks [NBX,..): histogram over 192-edge chunks; block NBX also does v1
__global__ __launch_bounds__(192) void k_front(
    const float* __restrict__ x, const float* __restrict__ Wn,
    const float* __restrict__ Watt, uint2* __restrict__ xph2,
    float* __restrict__ a0, float* __restrict__ a2,
    const int* __restrict__ ei, int* __restrict__ cnt,
    const float* __restrict__ We, float* __restrict__ v1, int E) {
    int t = threadIdx.x;
    int bx = blockIdx.x;
    if (bx >= NBX) {
        int e = (bx - NBX) * 192 + t;
        if (e < E) atomicAdd(&cnt[ei[E + e]], 1);
        if (bx == NBX && t < HEADS * 16) {
            int h = t / 16, k = t % 16;
            float s = 0.f;
            #pragma unroll
            for (int c = 0; c < CCH; ++c)
                s = fmaf(We[k * HC + h * CCH + c], Watt[h * HC + CCH + c], s);
            v1[t] = s;  // [h*16+k]
        }
        return;
    }
    __shared__ _Float16 pack[16 * CCH * 4];  // 8 KB: [j][c][h(4)]
    float wreg[CCH];
    #pragma unroll
    for (int k = 0; k < CCH; ++k) wreg[k] = Wn[k * HC + t];  // coalesced
    int base = bx * 16;
    int h = t >> 6, c = t & 63;
    float w0 = Watt[h * HC + c];
    float w2 = Watt[h * HC + 2 * CCH + c];
    int jmax = N_NODES - base; jmax = jmax > 16 ? 16 : jmax;
    #pragma unroll 1
    for (int j = 0; j < jmax; ++j) {
        const float* xr = x + (size_t)(base + j) * CCH;  // wave-uniform -> s_load
        float val = 0.f;
        #pragma unroll
        for (int k = 0; k < CCH; ++k) val = fmaf(xr[k], wreg[k], val);
        pack[(j * CCH + c) * 4 + h] = (_Float16)val;
        if (h == 0) pack[(j * CCH + c) * 4 + 3] = (_Float16)0.f;
        float p0 = val * w0, p2 = val * w2;
        #pragma unroll
        for (int off = 32; off; off >>= 1) {
            p0 += __shfl_down(p0, off);
            p2 += __shfl_down(p2, off);
        }
        if (c == 0) {
            a0[(base + j) * HEADS + h] = p0;
            a2[(base + j) * HEADS + h] = p2;
        }
    }
    __syncthreads();
    const uint2* p2v = (const uint2*)pack;
    for (int i = t; i < 16 * CCH; i += 192) {
        int n = base + (i >> 6);
        if (n < N_NODES) xph2[(size_t)base * CCH + i] = p2v[i];
    }
}

// ---------- k_scan49: bsum + exclusive scan + wave partition (1 launch) -----
__global__ __launch_bounds__(1024) void k_scan49(
    const int* __restrict__ cnt, int* __restrict__ off, int* __restrict__ cursor,
    int* __restrict__ wstart, int* __restrict__ bar, int* __restrict__ bsum,
    int E) {
    __shared__ int ws[16];
    __shared__ int bof_s;
    int b = blockIdx.x, t = threadIdx.x, lane = t & 63, wid = t >> 6;
    int i = b * 1024 + t;
    int v = (i < N_NODES) ? cnt[i] : 0;
    // phase A: block sums
    {
        int r = v;
        #pragma unroll
        for (int o = 32; o; o >>= 1) r += __shfl_down(r, o);
        if (lane == 0) ws[wid] = r;
        __syncthreads();
        if (wid == 0) {
            int s = (lane < 16) ? ws[lane] : 0;
            #pragma unroll
            for (int o = 8; o; o >>= 1) s += __shfl_down(s, o);
            if (lane == 0) bsum[b] = s;
        }
    }
    gbar(bar, 0, NSCAN);
    // phase B: local inclusive scan + block offset from bsum
    int x = v;
    #pragma unroll
    for (int o = 1; o < 64; o <<= 1) {
        int y = __shfl_up(x, o);
        if (lane >= o) x += y;
    }
    if (lane == 63) ws[wid] = x;
    __syncthreads();
    if (wid == 0) {
        int s = (lane < 16) ? ws[lane] : 0;
        #pragma unroll
        for (int o = 1; o < 16; o <<= 1) {
            int y = __shfl_up(s, o);
            if (lane >= o) s += y;
        }
        if (lane < 16) ws[lane] = s;
    } else if (wid == 1) {
        int bv = (lane < NSCAN) ? bsum[lane] : 0;
        int bx = bv;
        #pragma unroll
        for (int o = 1; o < 64; o <<= 1) {
            int y = __shfl_up(bx, o);
            if (lane >= o) bx += y;
        }
        if (lane == b) bof_s = bx - bv;
    }
    __syncthreads();
    int excl = bof_s + (wid ? ws[wid - 1] : 0) + x - v;
    if (i < N_NODES) { off[i] = excl; cursor[i] = excl; }
    if (b == 0 && t == 0) off[N_NODES] = E;
    gbar(bar, 1, NSCAN);
    // phase C: balanced partition (binary search), 50176 threads cover 12289
    int w = i;
    if (w <= NWAVES) {
        if (w == NWAVES) { wstart[NWAVES] = N_NODES; }
        else {
            long tgt = (long)E * w / NWAVES;
            int lo = 0, hi = N_NODES;  // first n with off[n] >= tgt
            while (lo < hi) {
                int mid = (lo + hi) >> 1;
                if (off[mid] < (int)tgt) lo = mid + 1; else hi = mid;
            }
            wstart[w] = lo;
        }
    }
}

// ---------- k_place: exp(alpha) + 48B record scatter (v1 via s_load) --------
__global__ __launch_bounds__(256) void k_place(
    const int* __restrict__ ei, const float* __restrict__ ea,
    const float* __restrict__ a0, const float* __restrict__ a2,
    const float* __restrict__ v1, int* __restrict__ cursor,
    float* __restrict__ recs, int E) {
    int e = blockIdx.x * 256 + threadIdx.x;
    if (e >= E) return;
    int src = ei[e], dst = ei[E + e];
    const float4* q = (const float4*)(ea + (size_t)e * 16);
    float4 q0 = q[0], q1 = q[1], q2 = q[2], q3 = q[3];
    float at[16] = {q0.x, q0.y, q0.z, q0.w, q1.x, q1.y, q1.z, q1.w,
                    q2.x, q2.y, q2.z, q2.w, q3.x, q3.y, q3.z, q3.w};
    float ex[HEADS];
    #pragma unroll
    for (int h = 0; h < HEADS; ++h) {
        float s = a0[dst * HEADS + h] + a2[src * HEADS + h];
        #pragma unroll
        for (int j = 0; j < 16; ++j) s = fmaf(at[j], v1[h * 16 + j], s);  // uniform
        s = (s >= 0.f) ? s : NEG_SLOPE * s;
        ex[h] = __expf(s);
    }
    int pos = atomicAdd(&cursor[dst], 1);
    float* rp = recs + (size_t)pos * 12;
    uint4 r0 = {hu(at[0], at[1]), hu(at[2], at[3]), hu(at[4], at[5]), hu(at[6], at[7])};
    uint4 r1 = {hu(at[8], at[9]), hu(at[10], at[11]), hu(at[12], at[13]), hu(at[14], at[15])};
    float4 r2 = {ex[0], ex[1], ex[2], __int_as_float(src)};
    *(uint4*)rp = r0;
    *(uint4*)(rp + 4) = r1;
    *(float4*)(rp + 8) = r2;
}

// ---------- k_msg: wave-per-node-run, pipelined, fdot2 inner, no LDS --------
// (unchanged from round 6/7: ~88 us measured, do not touch)
__global__ __launch_bounds__(256, 6) void k_msg(
    const int* __restrict__ off, const int* __restrict__ wstart,
    const float* __restrict__ recs, const uint2* __restrict__ xph2,
    const float* __restrict__ We, _Float16* __restrict__ rowsH) {
    int lane = threadIdx.x & 63;
    int w = blockIdx.x * 4 + (threadIdx.x >> 6);
    #define WP(h, q) hu(We[(2*(q)) * HC + (h) * CCH + lane], \
                        We[(2*(q)+1) * HC + (h) * CCH + lane])
    unsigned w00 = WP(0,0), w01 = WP(0,1), w02 = WP(0,2), w03 = WP(0,3),
             w04 = WP(0,4), w05 = WP(0,5), w06 = WP(0,6), w07 = WP(0,7);
    unsigned w10 = WP(1,0), w11 = WP(1,1), w12 = WP(1,2), w13 = WP(1,3),
             w14 = WP(1,4), w15 = WP(1,5), w16 = WP(1,6), w17 = WP(1,7);
    unsigned w20 = WP(2,0), w21 = WP(2,1), w22 = WP(2,2), w23 = WP(2,3),
             w24 = WP(2,4), w25 = WP(2,5), w26 = WP(2,6), w27 = WP(2,7);
    #undef WP

    int n0 = wstart[w], n1 = wstart[w + 1];
    n0 = __builtin_amdgcn_readfirstlane(n0);
    n1 = __builtin_amdgcn_readfirstlane(n1);
    if (n0 >= n1) return;

    int n = n0;
    int k    = __builtin_amdgcn_readfirstlane(off[n0]);
    int kend = __builtin_amdgcn_readfirstlane(off[n1]);
    int re   = __builtin_amdgcn_readfirstlane(off[n0 + 1]);

    float acc0 = 0.f, acc1 = 0.f, acc2 = 0.f;
    float den0 = 0.f, den1 = 0.f, den2 = 0.f;

    uint4 U0, U1; float4 RX; uint2 xv;
    if (k < kend) {
        const float* rp = recs + (size_t)k * 12;
        U0 = *(const uint4*)rp;
        U1 = *(const uint4*)(rp + 4);
        RX = *(const float4*)(rp + 8);
        int src = __builtin_amdgcn_readfirstlane(__float_as_int(RX.w));
        xv = xph2[(size_t)src * CCH + lane];
    }

    #define FLUSH(nn)                                                      \
        {                                                                  \
            size_t ro = (size_t)(nn) * HC + lane;                          \
            rowsH[ro]           = (_Float16)(acc0 / (den0 + 1e-16f));      \
            rowsH[ro + CCH]     = (_Float16)(acc1 / (den1 + 1e-16f));      \
            rowsH[ro + 2 * CCH] = (_Float16)(acc2 / (den2 + 1e-16f));      \
            acc0 = acc1 = acc2 = den0 = den1 = den2 = 0.f;                 \
        }

    while (k < kend) {
        while (k == re) {
            FLUSH(n);
            ++n;
            re = __builtin_amdgcn_readfirstlane(off[n + 1]);
        }
        int kn = (k + 1 < kend) ? k + 1 : k;
        const float* rpn = recs + (size_t)kn * 12;
        uint4 U0n = *(const uint4*)rpn;
        uint4 U1n = *(const uint4*)(rpn + 4);
        float4 RXn = *(const float4*)(rpn + 8);
        float ev0 = 0.f, ev1 = 0.f, ev2 = 0.f;
        #define D(u, wv, acc) acc = __builtin_amdgcn_fdot2(uh(u), uh(wv), acc, false);
        D(U0.x, w00, ev0) D(U0.x, w10, ev1) D(U0.x, w20, ev2)
        D(U0.y, w01, ev0) D(U0.y, w11, ev1) D(U0.y, w21, ev2)
        D(U0.z, w02, ev0) D(U0.z, w12, ev1) D(U0.z, w22, ev2)
        D(U0.w, w03, ev0) D(U0.w, w13, ev1) D(U0.w, w23, ev2)
        D(U1.x, w04, ev0) D(U1.x, w14, ev1) D(U1.x, w24, ev2)
        D(U1.y, w05, ev0) D(U1.y, w15, ev1) D(U1.y, w25, ev2)
        D(U1.z, w06, ev0) D(U1.z, w16, ev1) D(U1.z, w26, ev2)
        D(U1.w, w07, ev0) D(U1.w, w17, ev1) D(U1.w, w27, ev2)
        #undef D
        h2 xa = uh(xv.x), xb = uh(xv.y);
        den0 += RX.x; den1 += RX.y; den2 += RX.z;
        acc0 = fmaf(RX.x * ev0, (float)xa.x, acc0);
        acc1 = fmaf(RX.y * ev1, (float)xa.y, acc1);
        acc2 = fmaf(RX.z * ev2, (float)xb.x, acc2);
        U0 = U0n; U1 = U1n; RX = RXn;
        int src_n = __builtin_amdgcn_readfirstlane(__float_as_int(RXn.w));
        xv = xph2[(size_t)src_n * CCH + lane];
        ++k;
    }
    FLUSH(n);
    while (++n < n1) FLUSH(n);
    #undef FLUSH
}

// ---------- k_out: SMEM row broadcast + register fp16 Ws column, no LDS -----
__global__ __launch_bounds__(256) void k_out(
    const _Float16* __restrict__ rowsH, const float* __restrict__ Ws,
    const float* __restrict__ bias, float* __restrict__ out) {
    int lane = threadIdx.x & 63;
    int wgid = __builtin_amdgcn_readfirstlane(blockIdx.x * 4 + (threadIdx.x >> 6));
    float b = bias[lane];
    #define WQ(q) hu(Ws[(2*(q)) * CCH + lane], Ws[(2*(q)+1) * CCH + lane])
    unsigned s00=WQ(0),  s01=WQ(1),  s02=WQ(2),  s03=WQ(3),  s04=WQ(4),  s05=WQ(5),  s06=WQ(6),  s07=WQ(7);
    unsigned s08=WQ(8),  s09=WQ(9),  s10=WQ(10), s11=WQ(11), s12=WQ(12), s13=WQ(13), s14=WQ(14), s15=WQ(15);
    unsigned s16=WQ(16), s17=WQ(17), s18=WQ(18), s19=WQ(19), s20=WQ(20), s21=WQ(21), s22=WQ(22), s23=WQ(23);
    unsigned s24=WQ(24), s25=WQ(25), s26=WQ(26), s27=WQ(27), s28=WQ(28), s29=WQ(29), s30=WQ(30), s31=WQ(31);
    unsigned s32=WQ(32), s33=WQ(33), s34=WQ(34), s35=WQ(35), s36=WQ(36), s37=WQ(37), s38=WQ(38), s39=WQ(39);
    unsigned s40=WQ(40), s41=WQ(41), s42=WQ(42), s43=WQ(43), s44=WQ(44), s45=WQ(45), s46=WQ(46), s47=WQ(47);
    unsigned s48=WQ(48), s49=WQ(49), s50=WQ(50), s51=WQ(51), s52=WQ(52), s53=WQ(53), s54=WQ(54), s55=WQ(55);
    unsigned s56=WQ(56), s57=WQ(57), s58=WQ(58), s59=WQ(59), s60=WQ(60), s61=WQ(61), s62=WQ(62), s63=WQ(63);
    unsigned s64=WQ(64), s65=WQ(65), s66=WQ(66), s67=WQ(67), s68=WQ(68), s69=WQ(69), s70=WQ(70), s71=WQ(71);
    unsigned s72=WQ(72), s73=WQ(73), s74=WQ(74), s75=WQ(75), s76=WQ(76), s77=WQ(77), s78=WQ(78), s79=WQ(79);
    unsigned s80=WQ(80), s81=WQ(81), s82=WQ(82), s83=WQ(83), s84=WQ(84), s85=WQ(85), s86=WQ(86), s87=WQ(87);
    unsigned s88=WQ(88), s89=WQ(89), s90=WQ(90), s91=WQ(91), s92=WQ(92), s93=WQ(93), s94=WQ(94), s95=WQ(95);
    #undef WQ
    #pragma unroll 1
    for (int n = wgid; n < N_NODES; n += 1024) {
        const unsigned* rp = (const unsigned*)(rowsH + (size_t)n * HC);  // uniform
        float a0_ = b, a1_ = 0.f, a2_ = 0.f, a3_ = 0.f;
        #define DQ(q, sreg, acc) acc = __builtin_amdgcn_fdot2(uh(rp[q]), uh(sreg), acc, false);
        DQ(0,s00,a0_)  DQ(1,s01,a1_)  DQ(2,s02,a2_)  DQ(3,s03,a3_)
        DQ(4,s04,a0_)  DQ(5,s05,a1_)  DQ(6,s06,a2_)  DQ(7,s07,a3_)
        DQ(8,s08,a0_)  DQ(9,s09,a1_)  DQ(10,s10,a2_) DQ(11,s11,a3_)
        DQ(12,s12,a0_) DQ(13,s13,a1_) DQ(14,s14,a2_) DQ(15,s15,a3_)
        DQ(16,s16,a0_) DQ(17,s17,a1_) DQ(18,s18,a2_) DQ(19,s19,a3_)
        DQ(20,s20,a0_) DQ(21,s21,a1_) DQ(22,s22,a2_) DQ(23,s23,a3_)
        DQ(24,s24,a0_) DQ(25,s25,a1_) DQ(26,s26,a2_) DQ(27,s27,a3_)
        DQ(28,s28,a0_) DQ(29,s29,a1_) DQ(30,s30,a2_) DQ(31,s31,a3_)
        DQ(32,s32,a0_) DQ(33,s33,a1_) DQ(34,s34,a2_) DQ(35,s35,a3_)
        DQ(36,s36,a0_) DQ(37,s37,a1_) DQ(38,s38,a2_) DQ(39,s39,a3_)
        DQ(40,s40,a0_) DQ(41,s41,a1_) DQ(42,s42,a2_) DQ(43,s43,a3_)
        DQ(44,s44,a0_) DQ(45,s45,a1_) DQ(46,s46,a2_) DQ(47,s47,a3_)
        DQ(48,s48,a0_) DQ(49,s49,a1_) DQ(50,s50,a2_) DQ(51,s51,a3_)
        DQ(52,s52,a0_) DQ(53,s53,a1_) DQ(54,s54,a2_) DQ(55,s55,a3_)
        DQ(56,s56,a0_) DQ(57,s57,a1_) DQ(58,s58,a2_) DQ(59,s59,a3_)
        DQ(60,s60,a0_) DQ(61,s61,a1_) DQ(62,s62,a2_) DQ(63,s63,a3_)
        DQ(64,s64,a0_) DQ(65,s65,a1_) DQ(66,s66,a2_) DQ(67,s67,a3_)
        DQ(68,s68,a0_) DQ(69,s69,a1_) DQ(70,s70,a2_) DQ(71,s71,a3_)
        DQ(72,s72,a0_) DQ(73,s73,a1_) DQ(74,s74,a2_) DQ(75,s75,a3_)
        DQ(76,s76,a0_) DQ(77,s77,a1_) DQ(78,s78,a2_) DQ(79,s79,a3_)
        DQ(80,s80,a0_) DQ(81,s81,a1_) DQ(82,s82,a2_) DQ(83,s83,a3_)
        DQ(84,s84,a0_) DQ(85,s85,a1_) DQ(86,s86,a2_) DQ(87,s87,a3_)
        DQ(88,s88,a0_) DQ(89,s89,a1_) DQ(90,s90,a2_) DQ(91,s91,a3_)
        DQ(92,s92,a0_) DQ(93,s93,a1_) DQ(94,s94,a2_) DQ(95,s95,a3_)
        #undef DQ
        out[(size_t)n * CCH + lane] = (a0_ + a1_) + (a2_ + a3_);
    }
}

extern "C" void kernel_launch(void* const* d_in, const int* in_sizes, int n_in,
                              void* d_out, int out_size, void* d_ws, size_t ws_size,
                              hipStream_t stream) {
    const float* x    = (const float*)d_in[0];
    const int*   ei   = (const int*)d_in[1];
    const float* ea   = (const float*)d_in[2];
    const float* Wn   = (const float*)d_in[3];
    const float* We   = (const float*)d_in[4];
    const float* Watt = (const float*)d_in[5];
    const float* Ws   = (const float*)d_in[6];
    const float* bias = (const float*)d_in[7];
    float* out = (float*)d_out;

    const int E = in_sizes[1] / 2;

    // workspace layout (bytes, 16B-aligned regions); total ~85 MB
    char* w = (char*)d_ws;
    size_t o = 0;
    int*   cnt    = (int*)(w + o);    o += 50048 * 4;   // zeroed (with bar)
    int*   bar    = (int*)(w + o);    o += 16 * 4;      // zeroed (same memset)
    int*   off    = (int*)(w + o);    o += 50064 * 4;
    int*   cursor = (int*)(w + o);    o += 50048 * 4;
    int*   wst    = (int*)(w + o);    o += (NWAVES + 16) * 4;
    int*   bsum   = (int*)(w + o);    o += 64 * 4;
    float* v1     = (float*)(w + o);  o += 64 * 4;
    float* a0     = (float*)(w + o);  o += 150016 * 4;
    float* a2     = (float*)(w + o);  o += 150016 * 4;
    uint2* xph2   = (uint2*)(w + o);  o += (size_t)N_NODES * CCH * 8;
    _Float16* rowsH = (_Float16*)(w + o); o += (size_t)N_NODES * HC * 2;
    float* recs   = (float*)(w + o);  o += (size_t)E * 48;

    hipMemsetAsync(cnt, 0, (50048 + 16) * 4, stream);

    const int nbh = (E + 191) / 192;
    k_front<<<NBX + nbh, 192, 0, stream>>>(x, Wn, Watt, xph2, a0, a2,
                                           ei, cnt, We, v1, E);
    k_scan49<<<NSCAN, 1024, 0, stream>>>(cnt, off, cursor, wst, bar, bsum, E);
    k_place<<<(E + 255) / 256, 256, 0, stream>>>(ei, ea, a0, a2, v1, cursor, recs, E);
    k_msg<<<NWAVES / 4, 256, 0, stream>>>(off, wst, recs, xph2, We, rowsH);
    k_out<<<256, 256, 0, stream>>>(rowsH, Ws, bias, out);
}

// Round 9
// 362.846 us; speedup vs baseline: 3.0862x; 1.0256x over previous
//
#include <hip/hip_runtime.h>
#include <hip/hip_bf16.h>

// TripletMessage, CSR-grouped, atomic-free hot path.
// k_front: x_proj(fp16 packed) + a0/a2 + dst histogram + v1 precompute (fused).
// k_scan49: prefix-scan + balanced wave partition (grid barriers, 1 launch).
// k_place: ex[h]=exp(lrelu(a0+a2+<ea,v1>)), 48B CSR records {at fp16, ex, src}.
// k_msg: streams records (depth-2 pipeline), gathers packed-fp16 x_proj[src],
//        fdot2 e_ij, per-node flush.  k_out: rows @ Ws + bias (register Ws col).

#define N_NODES 50000
#define CCH 64
#define HEADS 3
#define HC 192
#define NEG_SLOPE 0.2f
#define NWAVES 12288   // k_msg: 3072 blocks x 4 waves
#define NBX 3125       // k_front xproj blocks (16 nodes each)
#define NSCAN 49       // scan blocks (49*1024 >= N_NODES)

typedef _Float16 h2 __attribute__((ext_vector_type(2)));
__device__ __forceinline__ h2 uh(unsigned u) {
    union { unsigned u; h2 h; } x; x.u = u; return x.h;
}
__device__ __forceinline__ unsigned hu(float a, float b) {
    union { unsigned u; _Float16 h[2]; } x;
    x.h[0] = (_Float16)a; x.h[1] = (_Float16)b; return x.u;
}

// device-scope grid barrier (all blocks resident; bar zeroed pre-launch)
__device__ __forceinline__ void gbar(int* bar, int phase, int nb) {
    __syncthreads();
    if (threadIdx.x == 0) {
        __threadfence();
        __hip_atomic_fetch_add(&bar[phase], 1, __ATOMIC_ACQ_REL,
                               __HIP_MEMORY_SCOPE_AGENT);
        while (__hip_atomic_load(&bar[phase], __ATOMIC_ACQUIRE,
                                 __HIP_MEMORY_SCOPE_AGENT) < nb) {}
        __threadfence();
    }
    __syncthreads();
}

// ---------- k_front: fused xproj | hist | prep ------------------------------
__global__ __launch_bounds__(192) void k_front(
    const float* __restrict__ x, const float* __restrict__ Wn,
    const float* __restrict__ Watt, uint2* __restrict__ xph2,
    float* __restrict__ a0, float* __restrict__ a2,
    const int* __restrict__ ei, int* __restrict__ cnt,
    const float* __restrict__ We, float* __restrict__ v1, int E) {
    int t = threadIdx.x;
    int bx = blockIdx.x;
    if (bx >= NBX) {
        int e = (bx - NBX) * 192 + t;
        if (e < E) atomicAdd(&cnt[ei[E + e]], 1);
        if (bx == NBX && t < HEADS * 16) {
            int h = t / 16, k = t % 16;
            float s = 0.f;
            #pragma unroll
            for (int c = 0; c < CCH; ++c)
                s = fmaf(We[k * HC + h * CCH + c], Watt[h * HC + CCH + c], s);
            v1[t] = s;  // [h*16+k]
        }
        return;
    }
    __shared__ _Float16 pack[16 * CCH * 4];  // 8 KB: [j][c][h(4)]
    float wreg[CCH];
    #pragma unroll
    for (int k = 0; k < CCH; ++k) wreg[k] = Wn[k * HC + t];  // coalesced
    int base = bx * 16;
    int h = t >> 6, c = t & 63;
    float w0 = Watt[h * HC + c];
    float w2 = Watt[h * HC + 2 * CCH + c];
    int jmax = N_NODES - base; jmax = jmax > 16 ? 16 : jmax;
    #pragma unroll 1
    for (int j = 0; j < jmax; ++j) {
        const float* xr = x + (size_t)(base + j) * CCH;  // wave-uniform -> s_load
        float val = 0.f;
        #pragma unroll
        for (int k = 0; k < CCH; ++k) val = fmaf(xr[k], wreg[k], val);
        pack[(j * CCH + c) * 4 + h] = (_Float16)val;
        if (h == 0) pack[(j * CCH + c) * 4 + 3] = (_Float16)0.f;
        float p0 = val * w0, p2 = val * w2;
        #pragma unroll
        for (int off = 32; off; off >>= 1) {
            p0 += __shfl_down(p0, off);
            p2 += __shfl_down(p2, off);
        }
        if (c == 0) {
            a0[(base + j) * HEADS + h] = p0;
            a2[(base + j) * HEADS + h] = p2;
        }
    }
    __syncthreads();
    const uint2* p2v = (const uint2*)pack;
    for (int i = t; i < 16 * CCH; i += 192) {
        int n = base + (i >> 6);
        if (n < N_NODES) xph2[(size_t)base * CCH + i] = p2v[i];
    }
}

// ---------- k_scan49: bsum + exclusive scan + wave partition (1 launch) -----
__global__ __launch_bounds__(1024) void k_scan49(
    const int* __restrict__ cnt, int* __restrict__ off, int* __restrict__ cursor,
    int* __restrict__ wstart, int* __restrict__ bar, int* __restrict__ bsum,
    int E) {
    __shared__ int ws[16];
    __shared__ int bof_s;
    int b = blockIdx.x, t = threadIdx.x, lane = t & 63, wid = t >> 6;
    int i = b * 1024 + t;
    int v = (i < N_NODES) ? cnt[i] : 0;
    {
        int r = v;
        #pragma unroll
        for (int o = 32; o; o >>= 1) r += __shfl_down(r, o);
        if (lane == 0) ws[wid] = r;
        __syncthreads();
        if (wid == 0) {
            int s = (lane < 16) ? ws[lane] : 0;
            #pragma unroll
            for (int o = 8; o; o >>= 1) s += __shfl_down(s, o);
            if (lane == 0) bsum[b] = s;
        }
    }
    gbar(bar, 0, NSCAN);
    int x = v;
    #pragma unroll
    for (int o = 1; o < 64; o <<= 1) {
        int y = __shfl_up(x, o);
        if (lane >= o) x += y;
    }
    if (lane == 63) ws[wid] = x;
    __syncthreads();
    if (wid == 0) {
        int s = (lane < 16) ? ws[lane] : 0;
        #pragma unroll
        for (int o = 1; o < 16; o <<= 1) {
            int y = __shfl_up(s, o);
            if (lane >= o) s += y;
        }
        if (lane < 16) ws[lane] = s;
    } else if (wid == 1) {
        int bv = (lane < NSCAN) ? bsum[lane] : 0;
        int bx = bv;
        #pragma unroll
        for (int o = 1; o < 64; o <<= 1) {
            int y = __shfl_up(bx, o);
            if (lane >= o) bx += y;
        }
        if (lane == b) bof_s = bx - bv;
    }
    __syncthreads();
    int excl = bof_s + (wid ? ws[wid - 1] : 0) + x - v;
    if (i < N_NODES) { off[i] = excl; cursor[i] = excl; }
    if (b == 0 && t == 0) off[N_NODES] = E;
    gbar(bar, 1, NSCAN);
    int w = i;
    if (w <= NWAVES) {
        if (w == NWAVES) { wstart[NWAVES] = N_NODES; }
        else {
            long tgt = (long)E * w / NWAVES;
            int lo = 0, hi = N_NODES;  // first n with off[n] >= tgt
            while (lo < hi) {
                int mid = (lo + hi) >> 1;
                if (off[mid] < (int)tgt) lo = mid + 1; else hi = mid;
            }
            wstart[w] = lo;
        }
    }
}

// ---------- k_place: exp(alpha) + 48B record scatter (v1 via s_load) --------
__global__ __launch_bounds__(256) void k_place(
    const int* __restrict__ ei, const float* __restrict__ ea,
    const float* __restrict__ a0, const float* __restrict__ a2,
    const float* __restrict__ v1, int* __restrict__ cursor,
    float* __restrict__ recs, int E) {
    int e = blockIdx.x * 256 + threadIdx.x;
    if (e >= E) return;
    int src = ei[e], dst = ei[E + e];
    const float4* q = (const float4*)(ea + (size_t)e * 16);
    float4 q0 = q[0], q1 = q[1], q2 = q[2], q3 = q[3];
    float at[16] = {q0.x, q0.y, q0.z, q0.w, q1.x, q1.y, q1.z, q1.w,
                    q2.x, q2.y, q2.z, q2.w, q3.x, q3.y, q3.z, q3.w};
    float ex[HEADS];
    #pragma unroll
    for (int h = 0; h < HEADS; ++h) {
        float s = a0[dst * HEADS + h] + a2[src * HEADS + h];
        #pragma unroll
        for (int j = 0; j < 16; ++j) s = fmaf(at[j], v1[h * 16 + j], s);  // uniform
        s = (s >= 0.f) ? s : NEG_SLOPE * s;
        ex[h] = __expf(s);
    }
    int pos = atomicAdd(&cursor[dst], 1);
    float* rp = recs + (size_t)pos * 12;
    uint4 r0 = {hu(at[0], at[1]), hu(at[2], at[3]), hu(at[4], at[5]), hu(at[6], at[7])};
    uint4 r1 = {hu(at[8], at[9]), hu(at[10], at[11]), hu(at[12], at[13]), hu(at[14], at[15])};
    float4 r2 = {ex[0], ex[1], ex[2], __int_as_float(src)};
    *(uint4*)rp = r0;
    *(uint4*)(rp + 4) = r1;
    *(float4*)(rp + 8) = r2;
}

// ---------- k_msg: wave-per-node-run, DEPTH-2 pipeline, fdot2, no LDS -------
__global__ __launch_bounds__(256, 6) void k_msg(
    const int* __restrict__ off, const int* __restrict__ wstart,
    const float* __restrict__ recs, const uint2* __restrict__ xph2,
    const float* __restrict__ We, _Float16* __restrict__ rowsH) {
    int lane = threadIdx.x & 63;
    int w = blockIdx.x * 4 + (threadIdx.x >> 6);
    #define WP(h, q) hu(We[(2*(q)) * HC + (h) * CCH + lane], \
                        We[(2*(q)+1) * HC + (h) * CCH + lane])
    unsigned w00 = WP(0,0), w01 = WP(0,1), w02 = WP(0,2), w03 = WP(0,3),
             w04 = WP(0,4), w05 = WP(0,5), w06 = WP(0,6), w07 = WP(0,7);
    unsigned w10 = WP(1,0), w11 = WP(1,1), w12 = WP(1,2), w13 = WP(1,3),
             w14 = WP(1,4), w15 = WP(1,5), w16 = WP(1,6), w17 = WP(1,7);
    unsigned w20 = WP(2,0), w21 = WP(2,1), w22 = WP(2,2), w23 = WP(2,3),
             w24 = WP(2,4), w25 = WP(2,5), w26 = WP(2,6), w27 = WP(2,7);
    #undef WP

    int n0 = wstart[w], n1 = wstart[w + 1];
    n0 = __builtin_amdgcn_readfirstlane(n0);
    n1 = __builtin_amdgcn_readfirstlane(n1);
    if (n0 >= n1) return;

    int n = n0;
    int k    = __builtin_amdgcn_readfirstlane(off[n0]);
    int kend = __builtin_amdgcn_readfirstlane(off[n1]);
    int re   = __builtin_amdgcn_readfirstlane(off[n0 + 1]);

    float acc0 = 0.f, acc1 = 0.f, acc2 = 0.f;
    float den0 = 0.f, den1 = 0.f, den2 = 0.f;

    // pipeline regs: stage A = edge k, stage B = edge k+1
    uint4 U0a, U1a, U0b, U1b; float4 RXa, RXb; uint2 xva, xvb;
    if (k < kend) {
        const float* rp = recs + (size_t)k * 12;
        U0a = *(const uint4*)rp;
        U1a = *(const uint4*)(rp + 4);
        RXa = *(const float4*)(rp + 8);
        int s0 = __builtin_amdgcn_readfirstlane(__float_as_int(RXa.w));
        xva = xph2[(size_t)s0 * CCH + lane];
        int k1 = (k + 1 < kend) ? k + 1 : k;
        const float* rq = recs + (size_t)k1 * 12;
        U0b = *(const uint4*)rq;
        U1b = *(const uint4*)(rq + 4);
        RXb = *(const float4*)(rq + 8);
        int s1 = __builtin_amdgcn_readfirstlane(__float_as_int(RXb.w));
        xvb = xph2[(size_t)s1 * CCH + lane];
    }

    #define FLUSH(nn)                                                      \
        {                                                                  \
            size_t ro = (size_t)(nn) * HC + lane;                          \
            rowsH[ro]           = (_Float16)(acc0 / (den0 + 1e-16f));      \
            rowsH[ro + CCH]     = (_Float16)(acc1 / (den1 + 1e-16f));      \
            rowsH[ro + 2 * CCH] = (_Float16)(acc2 / (den2 + 1e-16f));      \
            acc0 = acc1 = acc2 = den0 = den1 = den2 = 0.f;                 \
        }

    while (k < kend) {
        while (k == re) {  // wave-uniform node boundary
            FLUSH(n);
            ++n;
            re = __builtin_amdgcn_readfirstlane(off[n + 1]);
        }
        // prefetch record k+2 (sequential address, independent)
        int k2 = (k + 2 < kend) ? k + 2 : kend - 1;
        const float* rpn = recs + (size_t)k2 * 12;
        uint4 U0n = *(const uint4*)rpn;
        uint4 U1n = *(const uint4*)(rpn + 4);
        float4 RXn = *(const float4*)(rpn + 8);
        // compute edge k from stage A
        float ev0 = 0.f, ev1 = 0.f, ev2 = 0.f;
        #define D(u, wv, acc) acc = __builtin_amdgcn_fdot2(uh(u), uh(wv), acc, false);
        D(U0a.x, w00, ev0) D(U0a.x, w10, ev1) D(U0a.x, w20, ev2)
        D(U0a.y, w01, ev0) D(U0a.y, w11, ev1) D(U0a.y, w21, ev2)
        D(U0a.z, w02, ev0) D(U0a.z, w12, ev1) D(U0a.z, w22, ev2)
        D(U0a.w, w03, ev0) D(U0a.w, w13, ev1) D(U0a.w, w23, ev2)
        D(U1a.x, w04, ev0) D(U1a.x, w14, ev1) D(U1a.x, w24, ev2)
        D(U1a.y, w05, ev0) D(U1a.y, w15, ev1) D(U1a.y, w25, ev2)
        D(U1a.z, w06, ev0) D(U1a.z, w16, ev1) D(U1a.z, w26, ev2)
        D(U1a.w, w07, ev0) D(U1a.w, w17, ev1) D(U1a.w, w27, ev2)
        #undef D
        h2 xa = uh(xva.x), xb = uh(xva.y);
        den0 += RXa.x; den1 += RXa.y; den2 += RXa.z;
        acc0 = fmaf(RXa.x * ev0, (float)xa.x, acc0);
        acc1 = fmaf(RXa.y * ev1, (float)xa.y, acc1);
        acc2 = fmaf(RXa.z * ev2, (float)xb.x, acc2);
        // rotate stages; issue gather for edge k+2 (record already resident)
        U0a = U0b; U1a = U1b; RXa = RXb; xva = xvb;
        U0b = U0n; U1b = U1n; RXb = RXn;
        int s2 = __builtin_amdgcn_readfirstlane(__float_as_int(RXn.w));
        xvb = xph2[(size_t)s2 * CCH + lane];
        ++k;
    }
    FLUSH(n);
    while (++n < n1) FLUSH(n);
    #undef FLUSH
}

// ---------- k_out: SMEM row broadcast + register fp16 Ws column, no LDS -----
__global__ __launch_bounds__(256) void k_out(
    const _Float16* __restrict__ rowsH, const float* __restrict__ Ws,
    const float* __restrict__ bias, float* __restrict__ out) {
    int lane = threadIdx.x & 63;
    int wgid = __builtin_amdgcn_readfirstlane(blockIdx.x * 4 + (threadIdx.x >> 6));
    int stride = (int)gridDim.x * 4;
    float b = bias[lane];
    #define WQ(q) hu(Ws[(2*(q)) * CCH + lane], Ws[(2*(q)+1) * CCH + lane])
    unsigned s00=WQ(0),  s01=WQ(1),  s02=WQ(2),  s03=WQ(3),  s04=WQ(4),  s05=WQ(5),  s06=WQ(6),  s07=WQ(7);
    unsigned s08=WQ(8),  s09=WQ(9),  s10=WQ(10), s11=WQ(11), s12=WQ(12), s13=WQ(13), s14=WQ(14), s15=WQ(15);
    unsigned s16=WQ(16), s17=WQ(17), s18=WQ(18), s19=WQ(19), s20=WQ(20), s21=WQ(21), s22=WQ(22), s23=WQ(23);
    unsigned s24=WQ(24), s25=WQ(25), s26=WQ(26), s27=WQ(27), s28=WQ(28), s29=WQ(29), s30=WQ(30), s31=WQ(31);
    unsigned s32=WQ(32), s33=WQ(33), s34=WQ(34), s35=WQ(35), s36=WQ(36), s37=WQ(37), s38=WQ(38), s39=WQ(39);
    unsigned s40=WQ(40), s41=WQ(41), s42=WQ(42), s43=WQ(43), s44=WQ(44), s45=WQ(45), s46=WQ(46), s47=WQ(47);
    unsigned s48=WQ(48), s49=WQ(49), s50=WQ(50), s51=WQ(51), s52=WQ(52), s53=WQ(53), s54=WQ(54), s55=WQ(55);
    unsigned s56=WQ(56), s57=WQ(57), s58=WQ(58), s59=WQ(59), s60=WQ(60), s61=WQ(61), s62=WQ(62), s63=WQ(63);
    unsigned s64=WQ(64), s65=WQ(65), s66=WQ(66), s67=WQ(67), s68=WQ(68), s69=WQ(69), s70=WQ(70), s71=WQ(71);
    unsigned s72=WQ(72), s73=WQ(73), s74=WQ(74), s75=WQ(75), s76=WQ(76), s77=WQ(77), s78=WQ(78), s79=WQ(79);
    unsigned s80=WQ(80), s81=WQ(81), s82=WQ(82), s83=WQ(83), s84=WQ(84), s85=WQ(85), s86=WQ(86), s87=WQ(87);
    unsigned s88=WQ(88), s89=WQ(89), s90=WQ(90), s91=WQ(91), s92=WQ(92), s93=WQ(93), s94=WQ(94), s95=WQ(95);
    #undef WQ
    #pragma unroll 1
    for (int n = wgid; n < N_NODES; n += stride) {
        const unsigned* rp = (const unsigned*)(rowsH + (size_t)n * HC);  // uniform
        float a0_ = b, a1_ = 0.f, a2_ = 0.f, a3_ = 0.f;
        #define DQ(q, sreg, acc) acc = __builtin_amdgcn_fdot2(uh(rp[q]), uh(sreg), acc, false);
        DQ(0,s00,a0_)  DQ(1,s01,a1_)  DQ(2,s02,a2_)  DQ(3,s03,a3_)
        DQ(4,s04,a0_)  DQ(5,s05,a1_)  DQ(6,s06,a2_)  DQ(7,s07,a3_)
        DQ(8,s08,a0_)  DQ(9,s09,a1_)  DQ(10,s10,a2_) DQ(11,s11,a3_)
        DQ(12,s12,a0_) DQ(13,s13,a1_) DQ(14,s14,a2_) DQ(15,s15,a3_)
        DQ(16,s16,a0_) DQ(17,s17,a1_) DQ(18,s18,a2_) DQ(19,s19,a3_)
        DQ(20,s20,a0_) DQ(21,s21,a1_) DQ(22,s22,a2_) DQ(23,s23,a3_)
        DQ(24,s24,a0_) DQ(25,s25,a1_) DQ(26,s26,a2_) DQ(27,s27,a3_)
        DQ(28,s28,a0_) DQ(29,s29,a1_) DQ(30,s30,a2_) DQ(31,s31,a3_)
        DQ(32,s32,a0_) DQ(33,s33,a1_) DQ(34,s34,a2_) DQ(35,s35,a3_)
        DQ(36,s36,a0_) DQ(37,s37,a1_) DQ(38,s38,a2_) DQ(39,s39,a3_)
        DQ(40,s40,a0_) DQ(41,s41,a1_) DQ(42,s42,a2_) DQ(43,s43,a3_)
        DQ(44,s44,a0_) DQ(45,s45,a1_) DQ(46,s46,a2_) DQ(47,s47,a3_)
        DQ(48,s48,a0_) DQ(49,s49,a1_) DQ(50,s50,a2_) DQ(51,s51,a3_)
        DQ(52,s52,a0_) DQ(53,s53,a1_) DQ(54,s54,a2_) DQ(55,s55,a3_)
        DQ(56,s56,a0_) DQ(57,s57,a1_) DQ(58,s58,a2_) DQ(59,s59,a3_)
        DQ(60,s60,a0_) DQ(61,s61,a1_) DQ(62,s62,a2_) DQ(63,s63,a3_)
        DQ(64,s64,a0_) DQ(65,s65,a1_) DQ(66,s66,a2_) DQ(67,s67,a3_)
        DQ(68,s68,a0_) DQ(69,s69,a1_) DQ(70,s70,a2_) DQ(71,s71,a3_)
        DQ(72,s72,a0_) DQ(73,s73,a1_) DQ(74,s74,a2_) DQ(75,s75,a3_)
        DQ(76,s76,a0_) DQ(77,s77,a1_) DQ(78,s78,a2_) DQ(79,s79,a3_)
        DQ(80,s80,a0_) DQ(81,s81,a1_) DQ(82,s82,a2_) DQ(83,s83,a3_)
        DQ(84,s84,a0_) DQ(85,s85,a1_) DQ(86,s86,a2_) DQ(87,s87,a3_)
        DQ(88,s88,a0_) DQ(89,s89,a1_) DQ(90,s90,a2_) DQ(91,s91,a3_)
        DQ(92,s92,a0_) DQ(93,s93,a1_) DQ(94,s94,a2_) DQ(95,s95,a3_)
        #undef DQ
        out[(size_t)n * CCH + lane] = (a0_ + a1_) + (a2_ + a3_);
    }
}

extern "C" void kernel_launch(void* const* d_in, const int* in_sizes, int n_in,
                              void* d_out, int out_size, void* d_ws, size_t ws_size,
                              hipStream_t stream) {
    const float* x    = (const float*)d_in[0];
    const int*   ei   = (const int*)d_in[1];
    const float* ea   = (const float*)d_in[2];
    const float* Wn   = (const float*)d_in[3];
    const float* We   = (const float*)d_in[4];
    const float* Watt = (const float*)d_in[5];
    const float* Ws   = (const float*)d_in[6];
    const float* bias = (const float*)d_in[7];
    float* out = (float*)d_out;

    const int E = in_sizes[1] / 2;

    // workspace layout (bytes, 16B-aligned regions); total ~85 MB
    char* w = (char*)d_ws;
    size_t o = 0;
    int*   cnt    = (int*)(w + o);    o += 50048 * 4;   // zeroed (with bar)
    int*   bar    = (int*)(w + o);    o += 16 * 4;      // zeroed (same memset)
    int*   off    = (int*)(w + o);    o += 50064 * 4;
    int*   cursor = (int*)(w + o);    o += 50048 * 4;
    int*   wst    = (int*)(w + o);    o += (NWAVES + 16) * 4;
    int*   bsum   = (int*)(w + o);    o += 64 * 4;
    float* v1     = (float*)(w + o);  o += 64 * 4;
    float* a0     = (float*)(w + o);  o += 150016 * 4;
    float* a2     = (float*)(w + o);  o += 150016 * 4;
    uint2* xph2   = (uint2*)(w + o);  o += (size_t)N_NODES * CCH * 8;
    _Float16* rowsH = (_Float16*)(w + o); o += (size_t)N_NODES * HC * 2;
    float* recs   = (float*)(w + o);  o += (size_t)E * 48;

    hipMemsetAsync(cnt, 0, (50048 + 16) * 4, stream);

    const int nbh = (E + 191) / 192;
    k_front<<<NBX + nbh, 192, 0, stream>>>(x, Wn, Watt, xph2, a0, a2,
                                           ei, cnt, We, v1, E);
    k_scan49<<<NSCAN, 1024, 0, stream>>>(cnt, off, cursor, wst, bar, bsum, E);
    k_place<<<(E + 255) / 256, 256, 0, stream>>>(ei, ea, a0, a2, v1, cursor, recs, E);
    k_msg<<<NWAVES / 4, 256, 0, stream>>>(off, wst, recs, xph2, We, rowsH);
    k_out<<<768, 256, 0, stream>>>(rowsH, Ws, bias, out);
}